// Round 5
// baseline (295.129 us; speedup 1.0000x reference)
//
#include <hip/hip_runtime.h>

// MultiHeadAttention: B=2, S=4096, D=512, H=8, depth=64. fp32 in/out.
// mfma_f32_16x16x32_f16 everywhere, fp32 accum. S^T = K Q^T flash (one q-row
// per lane, register-shuffled P), async double-buffered global_load_lds
// staging in ALL matmul kernels. Round 16: R4 showed the kernel is
// latency-bound (MFMA 18 / VALU 45 / LDS ~55%, nothing saturated) at 21%
// occupancy (1024 blocks). KV-split 2 -> 4 restores 2048 blocks (~5
// co-resident blocks/CU) while keeping QBLK=32's halved per-work LDS
// traffic. Opart[0..2] overlays dead Qin/Kin/Vin, Opart[3] the old Ows
// slot; combine output moves to the dead Qws region. Defer-max (THR=8),
// v_max3 tree, dot2 psum retained.
#define NH   8
#define DH   64
#define NB   2
#define SEQ  4096
#define DM   512
#define MR   (NB * SEQ)
#define LSTR 72
#define LOG2E 1.44269504089f
#define NSPL 4
#define KVS  (SEQ / NSPL)
#define RH   (NB * NH * SEQ)   // 65536 q-rows per split

using f16x8 = __attribute__((ext_vector_type(8))) _Float16;
using f32x4 = __attribute__((ext_vector_type(4))) float;
using h2    = __attribute__((ext_vector_type(2))) _Float16;
#define MFMA16(a, b, c) __builtin_amdgcn_mfma_f32_16x16x32_f16(a, b, c, 0, 0, 0)

#if defined(__has_builtin) && __has_builtin(__builtin_amdgcn_exp2f)
#define EXP2(x) __builtin_amdgcn_exp2f(x)
#else
extern "C" __device__ float __ocml_native_exp2_f32(float);
#define EXP2(x) __ocml_native_exp2_f32(x)
#endif

__device__ __forceinline__ unsigned pk_f16(float a, float b) {
    typedef __fp16 fp16v2 __attribute__((ext_vector_type(2)));
    union { fp16v2 h; unsigned u; } c;
    c.h = __builtin_amdgcn_cvt_pkrtz(a, b);
    return c.u;
}
__device__ __forceinline__ unsigned sel_shfl(unsigned a, unsigned b, int pick, int src) {
    const unsigned va = __shfl(a, src);
    const unsigned vb = __shfl(b, src);
    return pick ? vb : va;
}
__device__ __forceinline__ float m3(float a, float b, float c) {
    return fmaxf(fmaxf(a, b), c);   // fuses to v_max3_f32
}
// l-sum accumulate from a packed f16 pair: c += p.lo + p.hi
__device__ __forceinline__ float dot2acc(unsigned u, float c) {
#if defined(__has_builtin) && __has_builtin(__builtin_amdgcn_fdot2)
    h2 a = __builtin_bit_cast(h2, u);
    h2 one = {(_Float16)1.f, (_Float16)1.f};
    return __builtin_amdgcn_fdot2(a, one, c, false);
#else
    h2 a = __builtin_bit_cast(h2, u);
    return c + (float)a[0] + (float)a[1];
#endif
}
// async 16B/lane global -> LDS (lds dest = wave-uniform base + lane*16)
__device__ __forceinline__ void async16(void* lds, const void* g) {
    __builtin_amdgcn_global_load_lds(
        (__attribute__((address_space(1))) void*)g,
        (__attribute__((address_space(3))) void*)lds, 16, 0, 0);
}

// ---------------------------------------------------------------------------
// W fp32 [k][n] -> Wt f16 [n][k], 4 weights. grid (8,8,4) x 256.
// ---------------------------------------------------------------------------
__global__ __launch_bounds__(256) void cvt_w(
    const float* __restrict__ w0, const float* __restrict__ w1,
    const float* __restrict__ w2, const float* __restrict__ w3,
    _Float16* __restrict__ Wt)
{
    __shared__ _Float16 T[64 * LSTR];
    const int z = blockIdx.z;
    const float* W = (z == 0) ? w0 : (z == 1 ? w1 : (z == 2 ? w2 : w3));
    _Float16* out = Wt + (size_t)z * DM * DM;
    const int t = threadIdx.x;
    const int k0 = blockIdx.x * 64, n0 = blockIdx.y * 64;
#pragma unroll
    for (int i = 0; i < 4; ++i) {
        const int kl  = i * 16 + (t >> 4);
        const int nl4 = (t & 15) * 4;
        float4 u = *(const float4*)(W + (size_t)(k0 + kl) * DM + n0 + nl4);
        T[(nl4 + 0) * LSTR + kl] = (_Float16)u.x;
        T[(nl4 + 1) * LSTR + kl] = (_Float16)u.y;
        T[(nl4 + 2) * LSTR + kl] = (_Float16)u.z;
        T[(nl4 + 3) * LSTR + kl] = (_Float16)u.w;
    }
    __syncthreads();
#pragma unroll
    for (int i = 0; i < 2; ++i) {
        const int nl = i * 32 + (t >> 3);
        const int kc = (t & 7) * 8;
        *(uint4*)(out + (size_t)(n0 + nl) * DM + k0 + kc) = *(const uint4*)&T[nl * LSTR + kc];
    }
}

// mask [B,1,1,S] fp32 -> mw = mask * (-1e9*log2e). grid 32 x 256.
__global__ __launch_bounds__(256) void maskprep(const float* __restrict__ mask,
                                                float* __restrict__ mw)
{
    const int i = blockIdx.x * 256 + threadIdx.x;
    mw[i] = mask[i] * (-1e9f * LOG2E);
}

// q,k,v fp32 -> f16 flat [MR][DM]. grid 6144 x 256, 8 elems/thread.
__global__ __launch_bounds__(256) void cvt_qkv(
    const float* __restrict__ q, const float* __restrict__ k,
    const float* __restrict__ v,
    _Float16* __restrict__ Qo, _Float16* __restrict__ Ko, _Float16* __restrict__ Vo)
{
    const size_t PER = (size_t)MR * DM;
    size_t base = ((size_t)blockIdx.x * 256 + threadIdx.x) * 8;
    const int tz = (int)(base / PER);
    const size_t off = base % PER;
    const float* s = (tz == 0) ? q : (tz == 1 ? k : v);
    _Float16* d    = (tz == 0) ? Qo : (tz == 1 ? Ko : Vo);
    float4 a = *(const float4*)(s + off);
    float4 b = *(const float4*)(s + off + 4);
    uint4 p = make_uint4(pk_f16(a.x, a.y), pk_f16(a.z, a.w),
                         pk_f16(b.x, b.y), pk_f16(b.z, b.w));
    *(uint4*)(d + off) = p;
}

// ---------------------------------------------------------------------------
// Fused QKV projection, async double-buffered. X f16 [M][512] by z;
// Wt f16 [3][n][k]. z<2: head-split f16 [B,H,S,64] (Q scaled by log2e);
// z==2: transposed [B,H,64,S]. grid (MR/128, 8, 3), block 256.
// LDS swizzle: chunk c -> row c>>3, slot c&7; data for column-chunk
// ((c&7)^(row&7)) stored there (swizzle applied on the global address side).
// ---------------------------------------------------------------------------
__global__ __launch_bounds__(256) void proj3(
    const _Float16* __restrict__ Qin, const _Float16* __restrict__ Kin,
    const _Float16* __restrict__ Vin, const _Float16* __restrict__ Wt,
    const float* __restrict__ bq, const float* __restrict__ bk,
    const float* __restrict__ bv,
    _Float16* __restrict__ Qo, _Float16* __restrict__ Ko,
    _Float16* __restrict__ VTo)
{
    __shared__ _Float16 Xs[2][128 * 64];
    __shared__ _Float16 Ws[2][64 * 64];

    const int z = blockIdx.z;
    const _Float16* X = (z == 0) ? Qin : (z == 1 ? Kin : Vin);
    const _Float16* W = Wt + (size_t)z * DM * DM;
    const float* bias = (z == 0) ? bq : (z == 1 ? bk : bv);
    const float scale = (z == 0) ? LOG2E : 1.0f;

    const int t = threadIdx.x;
    const int l = t & 63, w = t >> 6;
    const int m = l & 15, g = l >> 4;
    const int ms = m & 7;
    const int row0 = blockIdx.x * 128;
    const int col0 = blockIdx.y * 64;

    int xr[4], xsw[4];
#pragma unroll
    for (int i = 0; i < 4; ++i) {
        const int c = w * 256 + i * 64 + l;
        xr[i]  = c >> 3;
        xsw[i] = ((c & 7) ^ (xr[i] & 7)) * 8;
    }
    int wr[2], wsw[2];
#pragma unroll
    for (int i = 0; i < 2; ++i) {
        const int c = w * 128 + i * 64 + l;
        wr[i]  = c >> 3;
        wsw[i] = ((c & 7) ^ (wr[i] & 7)) * 8;
    }

    // prologue: k0 = 0 into buffer 0
#pragma unroll
    for (int i = 0; i < 4; ++i)
        async16(&Xs[0][(w * 256 + i * 64) * 8], X + (size_t)(row0 + xr[i]) * DM + xsw[i]);
#pragma unroll
    for (int i = 0; i < 2; ++i)
        async16(&Ws[0][(w * 128 + i * 64) * 8], W + (size_t)(col0 + wr[i]) * DM + wsw[i]);

    f32x4 acc[2][4] = {};

    for (int k0 = 0; k0 < DM; k0 += 64) {
        const int p = (k0 >> 6) & 1;
        __syncthreads();   // drains tile k0 (issued a full compute-phase ago)
        if (k0 + 64 < DM) {
            const int kn = k0 + 64;
#pragma unroll
            for (int i = 0; i < 4; ++i)
                async16(&Xs[p ^ 1][(w * 256 + i * 64) * 8],
                        X + (size_t)(row0 + xr[i]) * DM + kn + xsw[i]);
#pragma unroll
            for (int i = 0; i < 2; ++i)
                async16(&Ws[p ^ 1][(w * 128 + i * 64) * 8],
                        W + (size_t)(col0 + wr[i]) * DM + kn + wsw[i]);
        }
#pragma unroll
        for (int kk = 0; kk < 2; ++kk) {
            const int slot = ((kk * 4 + g) ^ ms) * 8;
            f16x8 a0 = *(const f16x8*)&Xs[p][(w * 32 + m) * 64 + slot];
            f16x8 a1 = *(const f16x8*)&Xs[p][(w * 32 + 16 + m) * 64 + slot];
#pragma unroll
            for (int ct = 0; ct < 4; ++ct) {
                f16x8 bf = *(const f16x8*)&Ws[p][(ct * 16 + m) * 64 + slot];
                acc[0][ct] = MFMA16(a0, bf, acc[0][ct]);
                acc[1][ct] = MFMA16(a1, bf, acc[1][ct]);
            }
        }
    }

    float bv4[4];
#pragma unroll
    for (int ct = 0; ct < 4; ++ct) bv4[ct] = bias[col0 + ct * 16 + m];

    if (z == 2) {
        __syncthreads();   // all waves done reading Xs
        _Float16* T = &Xs[0][0];   // reuse as T[64][136]
#pragma unroll
        for (int rt = 0; rt < 2; ++rt)
#pragma unroll
            for (int reg = 0; reg < 4; ++reg) {
                const int s_l = w * 32 + rt * 16 + g * 4 + reg;
#pragma unroll
                for (int ct = 0; ct < 4; ++ct) {
                    const int d = ct * 16 + m;
                    T[d * 136 + s_l] = (_Float16)(acc[rt][ct][reg] + bv4[ct]);
                }
            }
        __syncthreads();
        const int bb = row0 >> 12;
        const int s0 = row0 & (SEQ - 1);
#pragma unroll
        for (int j = 0; j < 4; ++j) {
            const int c = j * 256 + t;
            const int d = c >> 4;
            const int sc = (c & 15) * 8;
            *(uint4*)(VTo + (((size_t)bb * NH + blockIdx.y) * DH + d) * SEQ + s0 + sc) =
                *(const uint4*)&T[d * 136 + sc];
        }
    } else {
        _Float16* out = (z == 0) ? Qo : Ko;
#pragma unroll
        for (int rt = 0; rt < 2; ++rt)
#pragma unroll
            for (int reg = 0; reg < 4; ++reg) {
                const int row = row0 + w * 32 + rt * 16 + g * 4 + reg;
                const int bb = row >> 12;
                const int s  = row & (SEQ - 1);
#pragma unroll
                for (int ct = 0; ct < 4; ++ct)
                    out[(((size_t)bb * NH + blockIdx.y) * SEQ + s) * DH + ct * 16 + m] =
                        (_Float16)(scale * (acc[rt][ct][reg] + bv4[ct]));
            }
    }
}

// ---------------------------------------------------------------------------
// Output GEMM: d_out[M,512] fp32 = Ofin[M,512](f16) @ Wo + bo. Async dbuf.
// grid (MR/128, 8), block 256.
// ---------------------------------------------------------------------------
__global__ __launch_bounds__(256) void gemm_out(const _Float16* __restrict__ X,
                                                const _Float16* __restrict__ W,
                                                const float* __restrict__ bias,
                                                float* __restrict__ out)
{
    __shared__ _Float16 Xs[2][128 * 64];
    __shared__ _Float16 Ws[2][64 * 64];

    const int t = threadIdx.x;
    const int l = t & 63, w = t >> 6;
    const int m = l & 15, g = l >> 4;
    const int ms = m & 7;
    const int row0 = blockIdx.x * 128;
    const int col0 = blockIdx.y * 64;

    int xr[4], xsw[4];
#pragma unroll
    for (int i = 0; i < 4; ++i) {
        const int c = w * 256 + i * 64 + l;
        xr[i]  = c >> 3;
        xsw[i] = ((c & 7) ^ (xr[i] & 7)) * 8;
    }
    int wr[2], wsw[2];
#pragma unroll
    for (int i = 0; i < 2; ++i) {
        const int c = w * 128 + i * 64 + l;
        wr[i]  = c >> 3;
        wsw[i] = ((c & 7) ^ (wr[i] & 7)) * 8;
    }

#pragma unroll
    for (int i = 0; i < 4; ++i)
        async16(&Xs[0][(w * 256 + i * 64) * 8], X + (size_t)(row0 + xr[i]) * DM + xsw[i]);
#pragma unroll
    for (int i = 0; i < 2; ++i)
        async16(&Ws[0][(w * 128 + i * 64) * 8], W + (size_t)(col0 + wr[i]) * DM + wsw[i]);

    f32x4 acc[2][4] = {};

    for (int k0 = 0; k0 < DM; k0 += 64) {
        const int p = (k0 >> 6) & 1;
        __syncthreads();
        if (k0 + 64 < DM) {
            const int kn = k0 + 64;
#pragma unroll
            for (int i = 0; i < 4; ++i)
                async16(&Xs[p ^ 1][(w * 256 + i * 64) * 8],
                        X + (size_t)(row0 + xr[i]) * DM + kn + xsw[i]);
#pragma unroll
            for (int i = 0; i < 2; ++i)
                async16(&Ws[p ^ 1][(w * 128 + i * 64) * 8],
                        W + (size_t)(col0 + wr[i]) * DM + kn + wsw[i]);
        }
#pragma unroll
        for (int kk = 0; kk < 2; ++kk) {
            const int slot = ((kk * 4 + g) ^ ms) * 8;
            f16x8 a0 = *(const f16x8*)&Xs[p][(w * 32 + m) * 64 + slot];
            f16x8 a1 = *(const f16x8*)&Xs[p][(w * 32 + 16 + m) * 64 + slot];
#pragma unroll
            for (int ct = 0; ct < 4; ++ct) {
                f16x8 bf = *(const f16x8*)&Ws[p][(ct * 16 + m) * 64 + slot];
                acc[0][ct] = MFMA16(a0, bf, acc[0][ct]);
                acc[1][ct] = MFMA16(a1, bf, acc[1][ct]);
            }
        }
    }

    float bv4[4];
#pragma unroll
    for (int ct = 0; ct < 4; ++ct) bv4[ct] = bias[col0 + ct * 16 + m];

#pragma unroll
    for (int rt = 0; rt < 2; ++rt)
#pragma unroll
        for (int reg = 0; reg < 4; ++reg) {
            const int row = row0 + w * 32 + rt * 16 + g * 4 + reg;
#pragma unroll
            for (int ct = 0; ct < 4; ++ct)
                out[(size_t)row * DM + col0 + ct * 16 + m] = acc[rt][ct][reg] + bv4[ct];
        }
}

// ---------------------------------------------------------------------------
// Flash attention, KV-split x4, 32 q-rows per wave (two 16-row halves).
// Q(log2e-scaled),K f16 [B*H,S,64]; VT f16 [B*H,64,S]; mw fp32 [B][S]
// (pre-scaled mask, folded into the MFMA C-init). Split z covers kv in
// [z*1024, z*1024+1024); writes per-split-NORMALIZED partial into
// OpC (z<3, 3x8MB) / OpE (z==3) plus Ml f32x2 {m,l}[z*RH + row].
// grid (S/128, B*H, 4), block 256. Each K/V LDS fragment read feeds TWO
// MFMAs (one per q-half).
// ---------------------------------------------------------------------------
__global__ __launch_bounds__(256) void flash_mfma(
    const _Float16* __restrict__ Q, const _Float16* __restrict__ K,
    const _Float16* __restrict__ VT, const float* __restrict__ mw,
    _Float16* __restrict__ OpC, _Float16* __restrict__ OpE,
    float* __restrict__ Ml)
{
    __shared__ _Float16 Ks [2][64 * 64];
    __shared__ _Float16 VTs[2][64 * 64];

    const int t = threadIdx.x;
    const int l = t & 63, w = t >> 6;
    const int m = l & 15, g = l >> 4;
    const int bh = blockIdx.y;
    const int b  = bh >> 3;
    const int q0 = blockIdx.x * 128;
    const int z  = blockIdx.z;
    const int kb0 = z * KVS;

    const _Float16* Qh  = Q  + (size_t)bh * SEQ * DH;
    const _Float16* Kh  = K  + (size_t)bh * SEQ * DH;
    const _Float16* VTh = VT + (size_t)bh * DH * SEQ;
    const float* mwb = mw + (size_t)b * SEQ;

    _Float16* Opz = (z < 3) ? (OpC + (size_t)z * RH * DH) : OpE;

    const int c0 = w * 128 + l, c1 = c0 + 64;
    const int r0 = c0 >> 3,     r1 = c1 >> 3;
    const int cl0 = (c0 & 7) ^ (r0 & 7), cl1 = (c1 & 7) ^ (r1 & 7);
    const int    gK0 = r0 * DH + cl0 * 8, gK1 = r1 * DH + cl1 * 8;
    const size_t gV0 = (size_t)r0 * SEQ + cl0 * 8, gV1 = (size_t)r1 * SEQ + cl1 * 8;
    const int ldsA = w * 1024, ldsB = ldsA + 512;

    async16(&Ks[0][ldsA], Kh + (size_t)kb0 * DH + gK0);
    async16(&Ks[0][ldsB], Kh + (size_t)kb0 * DH + gK1);
    async16(&VTs[0][ldsA], VTh + kb0 + gV0);
    async16(&VTs[0][ldsB], VTh + kb0 + gV1);

    // Q fragments in registers: wave w covers q-rows q0 + w*32 + {0..15,16..31}
    f16x8 qf[2][2];
#pragma unroll
    for (int h = 0; h < 2; ++h)
#pragma unroll
        for (int kk = 0; kk < 2; ++kk)
            qf[h][kk] = *(const f16x8*)(Qh + (size_t)(q0 + w * 32 + h * 16 + m) * DH +
                                        kk * 32 + g * 8);

    float m_r[2] = {-INFINITY, -INFINITY}, l_r[2] = {0.f, 0.f};
    f32x4 oacc[2][4] = {};

    const int srcA = m + (((g * 2) & 3) << 4);
    const int srcB = m + (((g * 2 + 1) & 3) << 4);
    const int pick = g >> 1;
    const int ms = m & 7;

    for (int it = 0; it < KVS / 64; ++it) {
        const int t0 = kb0 + it * 64;
        const int p  = it & 1;
        __syncthreads();   // tile t0 landed

        if (it + 1 < KVS / 64) {
            const int tn = t0 + 64;
            async16(&Ks[p ^ 1][ldsA], Kh + (size_t)tn * DH + gK0);
            async16(&Ks[p ^ 1][ldsB], Kh + (size_t)tn * DH + gK1);
            async16(&VTs[p ^ 1][ldsA], VTh + tn + gV0);
            async16(&VTs[p ^ 1][ldsB], VTh + tn + gV1);
        }

        // ---- S^T = K Q^T + mask (mask pre-scaled, as MFMA C-init) ----
        f32x4 sacc[2][4];
#pragma unroll
        for (int kt = 0; kt < 4; ++kt) {
            const f32x4 mv = *(const f32x4*)&mwb[t0 + kt * 16 + g * 4];
            sacc[0][kt] = mv;
            sacc[1][kt] = mv;
        }
#pragma unroll
        for (int kk = 0; kk < 2; ++kk) {
            const int slot = ((kk * 4 + g) ^ ms) * 8;
#pragma unroll
            for (int kt = 0; kt < 4; ++kt) {
                f16x8 kf = *(const f16x8*)&Ks[p][(kt * 16 + m) * 64 + slot];
                sacc[0][kt] = MFMA16(kf, qf[0][kk], sacc[0][kt]);
                sacc[1][kt] = MFMA16(kf, qf[1][kk], sacc[1][kt]);
            }
        }

        // ---- online softmax per half, scalar state per lane ----
        float rmax[2];
#pragma unroll
        for (int h = 0; h < 2; ++h) {
            const float x0 = m3(sacc[h][0][0], sacc[h][0][1], sacc[h][0][2]);
            const float x1 = m3(sacc[h][0][3], sacc[h][1][0], sacc[h][1][1]);
            const float x2 = m3(sacc[h][1][2], sacc[h][1][3], sacc[h][2][0]);
            const float x3 = m3(sacc[h][2][1], sacc[h][2][2], sacc[h][2][3]);
            const float x4 = m3(sacc[h][3][0], sacc[h][3][1], sacc[h][3][2]);
            float r = fmaxf(m3(x0, x1, x2), m3(x3, x4, sacc[h][3][3]));
            r = fmaxf(r, __shfl_xor(r, 16));
            r = fmaxf(r, __shfl_xor(r, 32));
            rmax[h] = r;
        }

        // defer-max: only rescale when a max grew by more than 8
        // (P <= 2^8 = 256, safely inside f16 range; wave-uniform branch)
        if (!__all(rmax[0] <= m_r[0] + 8.f && rmax[1] <= m_r[1] + 8.f)) {
#pragma unroll
            for (int h = 0; h < 2; ++h) {
                const float mnew  = fmaxf(m_r[h], rmax[h]);
                const float alpha = EXP2(m_r[h] - mnew);   // first tile: 0
                m_r[h] = mnew;
                l_r[h] *= alpha;
#pragma unroll
                for (int dt = 0; dt < 4; ++dt)
#pragma unroll
                    for (int r = 0; r < 4; ++r) oacc[h][dt][r] *= alpha;
            }
        }

        unsigned pkw[2][4][2];
#pragma unroll
        for (int h = 0; h < 2; ++h) {
            float ps0 = 0.f, ps1 = 0.f;
#pragma unroll
            for (int kt = 0; kt < 4; ++kt) {
                const float p0 = EXP2(sacc[h][kt][0] - m_r[h]);
                const float p1 = EXP2(sacc[h][kt][1] - m_r[h]);
                const float p2 = EXP2(sacc[h][kt][2] - m_r[h]);
                const float p3 = EXP2(sacc[h][kt][3] - m_r[h]);
                pkw[h][kt][0] = pk_f16(p0, p1);
                pkw[h][kt][1] = pk_f16(p2, p3);
                if (kt < 2) {
                    ps0 = dot2acc(pkw[h][kt][0], ps0);
                    ps0 = dot2acc(pkw[h][kt][1], ps0);
                } else {
                    ps1 = dot2acc(pkw[h][kt][0], ps1);
                    ps1 = dot2acc(pkw[h][kt][1], ps1);
                }
            }
            l_r[h] += ps0 + ps1;
        }

        // ---- O^T += V^T P^T ; B-frags assembled by register shuffle;
        //      each vf read feeds both q-halves ----
#pragma unroll
        for (int kk = 0; kk < 2; ++kk) {
            union { unsigned u[4]; f16x8 h; } pf[2];
#pragma unroll
            for (int h = 0; h < 2; ++h) {
                pf[h].u[0] = sel_shfl(pkw[h][2 * kk][0], pkw[h][2 * kk + 1][0], pick, srcA);
                pf[h].u[1] = sel_shfl(pkw[h][2 * kk][1], pkw[h][2 * kk + 1][1], pick, srcA);
                pf[h].u[2] = sel_shfl(pkw[h][2 * kk][0], pkw[h][2 * kk + 1][0], pick, srcB);
                pf[h].u[3] = sel_shfl(pkw[h][2 * kk][1], pkw[h][2 * kk + 1][1], pick, srcB);
            }
            const int slot = ((kk * 4 + g) ^ ms) * 8;
#pragma unroll
            for (int dt = 0; dt < 4; ++dt) {
                f16x8 vf = *(const f16x8*)&VTs[p][(dt * 16 + m) * 64 + slot];
                oacc[0][dt] = MFMA16(vf, pf[0].h, oacc[0][dt]);
                oacc[1][dt] = MFMA16(vf, pf[1].h, oacc[1][dt]);
            }
        }
    }

    // ---- final l reduction + per-split-normalized partial store ----
#pragma unroll
    for (int h = 0; h < 2; ++h) {
        float lv = l_r[h];
        lv += __shfl_xor(lv, 16);
        lv += __shfl_xor(lv, 32);
        const float inv = 1.0f / lv;
        const int q = q0 + w * 32 + h * 16 + m;
        const size_t row = (size_t)bh * SEQ + q;
        _Float16* Orow = Opz + row * DH;
#pragma unroll
        for (int dt = 0; dt < 4; ++dt) {
            _Float16 o4[4] = { (_Float16)(oacc[h][dt][0] * inv),
                               (_Float16)(oacc[h][dt][1] * inv),
                               (_Float16)(oacc[h][dt][2] * inv),
                               (_Float16)(oacc[h][dt][3] * inv) };
            *(uint2*)(Orow + dt * 16 + g * 4) = *(const uint2*)o4;
        }
        if (g == 0) ((float2*)Ml)[(size_t)z * RH + row] = make_float2(m_r[h], lv);
    }
}

// ---------------------------------------------------------------------------
// Combine the 4 KV-splits: O = sum_z a_z O_z / sum_z a_z,
// a_z = exp2(m_z - M) * l_z  (exact, defer-max-safe). 16 threads per q-row,
// 4 d each. grid (RH*16/256) x 256. Writes O f16 [B,S,512].
// ---------------------------------------------------------------------------
__global__ __launch_bounds__(256) void combine(const _Float16* __restrict__ OpC,
                                               const _Float16* __restrict__ OpE,
                                               const float* __restrict__ Ml,
                                               _Float16* __restrict__ O)
{
    const int i = blockIdx.x * 256 + threadIdx.x;
    const int r = i >> 4;            // bh*SEQ + q
    const int dq = (i & 15) * 4;
    float2 ml[NSPL];
#pragma unroll
    for (int zz = 0; zz < NSPL; ++zz)
        ml[zz] = ((const float2*)Ml)[(size_t)zz * RH + r];
    float M = fmaxf(fmaxf(ml[0].x, ml[1].x), fmaxf(ml[2].x, ml[3].x));
    float a[NSPL], s = 0.f;
#pragma unroll
    for (int zz = 0; zz < NSPL; ++zz) {
        a[zz] = EXP2(ml[zz].x - M) * ml[zz].y;
        s += a[zz];
    }
    const float inv = 1.f / s;
    float acc4[4] = {0.f, 0.f, 0.f, 0.f};
#pragma unroll
    for (int zz = 0; zz < NSPL; ++zz) {
        const _Float16* base = (zz < 3) ? (OpC + (size_t)zz * RH * DH) : OpE;
        union { uint2 u; _Float16 h[4]; } v;
        v.u = *(const uint2*)(base + (size_t)r * DH + dq);
#pragma unroll
        for (int j = 0; j < 4; ++j) acc4[j] += a[zz] * (float)v.h[j];
    }
    union { uint2 u; _Float16 h[4]; } o;
#pragma unroll
    for (int j = 0; j < 4; ++j) o.h[j] = (_Float16)(acc4[j] * inv);
    const int bh = r >> 12, q = r & (SEQ - 1);
    const int b = bh >> 3, h = bh & 7;
    *(uint2*)(O + ((size_t)b * SEQ + q) * DM + h * DH + dq) = o.u;
}

extern "C" void kernel_launch(void* const* d_in, const int* in_sizes, int n_in,
                              void* d_out, int out_size, void* d_ws, size_t ws_size,
                              hipStream_t stream) {
    const float* q    = (const float*)d_in[0];
    const float* k    = (const float*)d_in[1];
    const float* v    = (const float*)d_in[2];
    const float* mask = (const float*)d_in[3];
    const float* wq   = (const float*)d_in[4];
    const float* bq   = (const float*)d_in[5];
    const float* wk   = (const float*)d_in[6];
    const float* bk   = (const float*)d_in[7];
    const float* wv   = (const float*)d_in[8];
    const float* bv   = (const float*)d_in[9];
    const float* wo   = (const float*)d_in[10];
    const float* bo   = (const float*)d_in[11];

    // workspace (~60 MB):
    //   Wt 2MB | mw 32KB | Qin,Kin,Vin 24MB | Qws,Kws,VTws 24MB | OpE 8MB | Ml 2MB
    // Lifetimes: Qin..Vin dead after proj3 -> Opart[0..2] (OpC).
    //            OpE = old Ows slot -> Opart[3].
    //            Qws dead after flash -> combine output Ofin; gemm_out reads it.
    const size_t P8 = (size_t)MR * DM;   // 4,194,304 elems = 8MB f16 = RH*DH
    _Float16* Wt  = (_Float16*)d_ws;
    float*    mw  = (float*)(Wt + (size_t)4 * DM * DM);
    _Float16* Qin = (_Float16*)(mw + NB * SEQ);
    _Float16* Kin = Qin + P8;
    _Float16* Vin = Kin + P8;
    _Float16* Qws = Vin + P8;
    _Float16* Kws = Qws + P8;
    _Float16* VTws = Kws + P8;
    _Float16* OpE  = VTws + P8;          // 8MB (split 3 partial)
    float*    Mlb  = (float*)(OpE + P8); // 2MB

    _Float16* OpC  = Qin;                // splits 0..2 partials (24MB)
    _Float16* Ofin = Qws;                // combine output, read by gemm_out

    cvt_w<<<dim3(8, 8, 4), 256, 0, stream>>>(wq, wk, wv, wo, Wt);
    maskprep<<<dim3(NB * SEQ / 256), 256, 0, stream>>>(mask, mw);
    cvt_qkv<<<dim3(3 * (MR * DM / 8) / 256), 256, 0, stream>>>(q, k, v, Qin, Kin, Vin);

    proj3<<<dim3(MR / 128, DM / 64, 3), 256, 0, stream>>>(
        Qin, Kin, Vin, Wt, bq, bk, bv, Qws, Kws, VTws);

    flash_mfma<<<dim3(SEQ / 128, NB * NH, NSPL), 256, 0, stream>>>(
        Qws, Kws, VTws, mw, OpC, OpE, Mlb);

    combine<<<dim3(RH * 16 / 256), 256, 0, stream>>>(OpC, OpE, Mlb, Ofin);

    gemm_out<<<dim3(MR / 128, DM / 64), 256, 0, stream>>>(
        Ofin, Wt + (size_t)3 * DM * DM, bo, (float*)d_out);
}

// Round 6
// 281.985 us; speedup vs baseline: 1.0466x; 1.0466x over previous
//
#include <hip/hip_runtime.h>

// MultiHeadAttention: B=2, S=4096, D=512, H=8, depth=64. fp32 in/out.
// mfma_f32_16x16x32_f16 everywhere, fp32 accum. S^T = K Q^T flash (one q-row
// per lane), async double-buffered global_load_lds staging in ALL matmul
// kernels. Round 17: back to the best-measured R1 config (QBLK=16, NSPL=2,
// ~39% occupancy; QBLK=32 variants are register-capped at ~2 blocks/CU and
// gained nothing). P-gather for the PV B-frag moved from 16 ds_bpermute +
// 8 cndmask (the top LDS consumer and the source of ~all 8.4M bank-conflict
// cycles) to a wave-private LDS round-trip: 4 ds_write_b64 + 2 ds_read_b128
// per tile, stride-36 rows (aligned, ~uniform banks). Defer-max check is now
// lane-local (no ds_swizzle on the common path). v_max3 tree, dot2 psum,
// mask-as-C-init retained.
#define NH   8
#define DH   64
#define NB   2
#define SEQ  4096
#define DM   512
#define MR   (NB * SEQ)
#define LSTR 72
#define LOG2E 1.44269504089f
#define NSPL 2
#define KVS  (SEQ / NSPL)
#define RH   (NB * NH * SEQ)   // 65536 q-rows across heads/splits
#define PSTR 36                // P_lds row stride in u32 (even, mult of 4)

using f16x8 = __attribute__((ext_vector_type(8))) _Float16;
using f32x4 = __attribute__((ext_vector_type(4))) float;
using h2    = __attribute__((ext_vector_type(2))) _Float16;
#define MFMA16(a, b, c) __builtin_amdgcn_mfma_f32_16x16x32_f16(a, b, c, 0, 0, 0)

#if defined(__has_builtin) && __has_builtin(__builtin_amdgcn_exp2f)
#define EXP2(x) __builtin_amdgcn_exp2f(x)
#else
extern "C" __device__ float __ocml_native_exp2_f32(float);
#define EXP2(x) __ocml_native_exp2_f32(x)
#endif

__device__ __forceinline__ unsigned pk_f16(float a, float b) {
    typedef __fp16 fp16v2 __attribute__((ext_vector_type(2)));
    union { fp16v2 h; unsigned u; } c;
    c.h = __builtin_amdgcn_cvt_pkrtz(a, b);
    return c.u;
}
__device__ __forceinline__ float m3(float a, float b, float c) {
    return fmaxf(fmaxf(a, b), c);   // fuses to v_max3_f32
}
// l-sum accumulate from a packed f16 pair: c += p.lo + p.hi
__device__ __forceinline__ float dot2acc(unsigned u, float c) {
#if defined(__has_builtin) && __has_builtin(__builtin_amdgcn_fdot2)
    h2 a = __builtin_bit_cast(h2, u);
    h2 one = {(_Float16)1.f, (_Float16)1.f};
    return __builtin_amdgcn_fdot2(a, one, c, false);
#else
    h2 a = __builtin_bit_cast(h2, u);
    return c + (float)a[0] + (float)a[1];
#endif
}
// async 16B/lane global -> LDS (lds dest = wave-uniform base + lane*16)
__device__ __forceinline__ void async16(void* lds, const void* g) {
    __builtin_amdgcn_global_load_lds(
        (__attribute__((address_space(1))) void*)g,
        (__attribute__((address_space(3))) void*)lds, 16, 0, 0);
}

// ---------------------------------------------------------------------------
// W fp32 [k][n] -> Wt f16 [n][k], 4 weights. grid (8,8,4) x 256.
// ---------------------------------------------------------------------------
__global__ __launch_bounds__(256) void cvt_w(
    const float* __restrict__ w0, const float* __restrict__ w1,
    const float* __restrict__ w2, const float* __restrict__ w3,
    _Float16* __restrict__ Wt)
{
    __shared__ _Float16 T[64 * LSTR];
    const int z = blockIdx.z;
    const float* W = (z == 0) ? w0 : (z == 1 ? w1 : (z == 2 ? w2 : w3));
    _Float16* out = Wt + (size_t)z * DM * DM;
    const int t = threadIdx.x;
    const int k0 = blockIdx.x * 64, n0 = blockIdx.y * 64;
#pragma unroll
    for (int i = 0; i < 4; ++i) {
        const int kl  = i * 16 + (t >> 4);
        const int nl4 = (t & 15) * 4;
        float4 u = *(const float4*)(W + (size_t)(k0 + kl) * DM + n0 + nl4);
        T[(nl4 + 0) * LSTR + kl] = (_Float16)u.x;
        T[(nl4 + 1) * LSTR + kl] = (_Float16)u.y;
        T[(nl4 + 2) * LSTR + kl] = (_Float16)u.z;
        T[(nl4 + 3) * LSTR + kl] = (_Float16)u.w;
    }
    __syncthreads();
#pragma unroll
    for (int i = 0; i < 2; ++i) {
        const int nl = i * 32 + (t >> 3);
        const int kc = (t & 7) * 8;
        *(uint4*)(out + (size_t)(n0 + nl) * DM + k0 + kc) = *(const uint4*)&T[nl * LSTR + kc];
    }
}

// mask [B,1,1,S] fp32 -> mw = mask * (-1e9*log2e). grid 32 x 256.
__global__ __launch_bounds__(256) void maskprep(const float* __restrict__ mask,
                                                float* __restrict__ mw)
{
    const int i = blockIdx.x * 256 + threadIdx.x;
    mw[i] = mask[i] * (-1e9f * LOG2E);
}

// q,k,v fp32 -> f16 flat [MR][DM]. grid 6144 x 256, 8 elems/thread.
__global__ __launch_bounds__(256) void cvt_qkv(
    const float* __restrict__ q, const float* __restrict__ k,
    const float* __restrict__ v,
    _Float16* __restrict__ Qo, _Float16* __restrict__ Ko, _Float16* __restrict__ Vo)
{
    const size_t PER = (size_t)MR * DM;
    size_t base = ((size_t)blockIdx.x * 256 + threadIdx.x) * 8;
    const int tz = (int)(base / PER);
    const size_t off = base % PER;
    const float* s = (tz == 0) ? q : (tz == 1 ? k : v);
    _Float16* d    = (tz == 0) ? Qo : (tz == 1 ? Ko : Vo);
    float4 a = *(const float4*)(s + off);
    float4 b = *(const float4*)(s + off + 4);
    uint4 p = make_uint4(pk_f16(a.x, a.y), pk_f16(a.z, a.w),
                         pk_f16(b.x, b.y), pk_f16(b.z, b.w));
    *(uint4*)(d + off) = p;
}

// ---------------------------------------------------------------------------
// Fused QKV projection, async double-buffered. X f16 [M][512] by z;
// Wt f16 [3][n][k]. z<2: head-split f16 [B,H,S,64] (Q scaled by log2e);
// z==2: transposed [B,H,64,S]. grid (MR/128, 8, 3), block 256.
// LDS swizzle: chunk c -> row c>>3, slot c&7; data for column-chunk
// ((c&7)^(row&7)) stored there (swizzle applied on the global address side).
// ---------------------------------------------------------------------------
__global__ __launch_bounds__(256) void proj3(
    const _Float16* __restrict__ Qin, const _Float16* __restrict__ Kin,
    const _Float16* __restrict__ Vin, const _Float16* __restrict__ Wt,
    const float* __restrict__ bq, const float* __restrict__ bk,
    const float* __restrict__ bv,
    _Float16* __restrict__ Qo, _Float16* __restrict__ Ko,
    _Float16* __restrict__ VTo)
{
    __shared__ _Float16 Xs[2][128 * 64];
    __shared__ _Float16 Ws[2][64 * 64];

    const int z = blockIdx.z;
    const _Float16* X = (z == 0) ? Qin : (z == 1 ? Kin : Vin);
    const _Float16* W = Wt + (size_t)z * DM * DM;
    const float* bias = (z == 0) ? bq : (z == 1 ? bk : bv);
    const float scale = (z == 0) ? LOG2E : 1.0f;

    const int t = threadIdx.x;
    const int l = t & 63, w = t >> 6;
    const int m = l & 15, g = l >> 4;
    const int ms = m & 7;
    const int row0 = blockIdx.x * 128;
    const int col0 = blockIdx.y * 64;

    int xr[4], xsw[4];
#pragma unroll
    for (int i = 0; i < 4; ++i) {
        const int c = w * 256 + i * 64 + l;
        xr[i]  = c >> 3;
        xsw[i] = ((c & 7) ^ (xr[i] & 7)) * 8;
    }
    int wr[2], wsw[2];
#pragma unroll
    for (int i = 0; i < 2; ++i) {
        const int c = w * 128 + i * 64 + l;
        wr[i]  = c >> 3;
        wsw[i] = ((c & 7) ^ (wr[i] & 7)) * 8;
    }

    // prologue: k0 = 0 into buffer 0
#pragma unroll
    for (int i = 0; i < 4; ++i)
        async16(&Xs[0][(w * 256 + i * 64) * 8], X + (size_t)(row0 + xr[i]) * DM + xsw[i]);
#pragma unroll
    for (int i = 0; i < 2; ++i)
        async16(&Ws[0][(w * 128 + i * 64) * 8], W + (size_t)(col0 + wr[i]) * DM + wsw[i]);

    f32x4 acc[2][4] = {};

    for (int k0 = 0; k0 < DM; k0 += 64) {
        const int p = (k0 >> 6) & 1;
        __syncthreads();   // drains tile k0 (issued a full compute-phase ago)
        if (k0 + 64 < DM) {
            const int kn = k0 + 64;
#pragma unroll
            for (int i = 0; i < 4; ++i)
                async16(&Xs[p ^ 1][(w * 256 + i * 64) * 8],
                        X + (size_t)(row0 + xr[i]) * DM + kn + xsw[i]);
#pragma unroll
            for (int i = 0; i < 2; ++i)
                async16(&Ws[p ^ 1][(w * 128 + i * 64) * 8],
                        W + (size_t)(col0 + wr[i]) * DM + kn + wsw[i]);
        }
#pragma unroll
        for (int kk = 0; kk < 2; ++kk) {
            const int slot = ((kk * 4 + g) ^ ms) * 8;
            f16x8 a0 = *(const f16x8*)&Xs[p][(w * 32 + m) * 64 + slot];
            f16x8 a1 = *(const f16x8*)&Xs[p][(w * 32 + 16 + m) * 64 + slot];
#pragma unroll
            for (int ct = 0; ct < 4; ++ct) {
                f16x8 bf = *(const f16x8*)&Ws[p][(ct * 16 + m) * 64 + slot];
                acc[0][ct] = MFMA16(a0, bf, acc[0][ct]);
                acc[1][ct] = MFMA16(a1, bf, acc[1][ct]);
            }
        }
    }

    float bv4[4];
#pragma unroll
    for (int ct = 0; ct < 4; ++ct) bv4[ct] = bias[col0 + ct * 16 + m];

    if (z == 2) {
        __syncthreads();   // all waves done reading Xs
        _Float16* T = &Xs[0][0];   // reuse as T[64][136]
#pragma unroll
        for (int rt = 0; rt < 2; ++rt)
#pragma unroll
            for (int reg = 0; reg < 4; ++reg) {
                const int s_l = w * 32 + rt * 16 + g * 4 + reg;
#pragma unroll
                for (int ct = 0; ct < 4; ++ct) {
                    const int d = ct * 16 + m;
                    T[d * 136 + s_l] = (_Float16)(acc[rt][ct][reg] + bv4[ct]);
                }
            }
        __syncthreads();
        const int bb = row0 >> 12;
        const int s0 = row0 & (SEQ - 1);
#pragma unroll
        for (int j = 0; j < 4; ++j) {
            const int c = j * 256 + t;
            const int d = c >> 4;
            const int sc = (c & 15) * 8;
            *(uint4*)(VTo + (((size_t)bb * NH + blockIdx.y) * DH + d) * SEQ + s0 + sc) =
                *(const uint4*)&T[d * 136 + sc];
        }
    } else {
        _Float16* out = (z == 0) ? Qo : Ko;
#pragma unroll
        for (int rt = 0; rt < 2; ++rt)
#pragma unroll
            for (int reg = 0; reg < 4; ++reg) {
                const int row = row0 + w * 32 + rt * 16 + g * 4 + reg;
                const int bb = row >> 12;
                const int s  = row & (SEQ - 1);
#pragma unroll
                for (int ct = 0; ct < 4; ++ct)
                    out[(((size_t)bb * NH + blockIdx.y) * SEQ + s) * DH + ct * 16 + m] =
                        (_Float16)(scale * (acc[rt][ct][reg] + bv4[ct]));
            }
    }
}

// ---------------------------------------------------------------------------
// Output GEMM: d_out[M,512] fp32 = Ows[M,512](f16) @ Wo + bo. Async dbuf.
// grid (MR/128, 8), block 256.
// ---------------------------------------------------------------------------
__global__ __launch_bounds__(256) void gemm_out(const _Float16* __restrict__ X,
                                                const _Float16* __restrict__ W,
                                                const float* __restrict__ bias,
                                                float* __restrict__ out)
{
    __shared__ _Float16 Xs[2][128 * 64];
    __shared__ _Float16 Ws[2][64 * 64];

    const int t = threadIdx.x;
    const int l = t & 63, w = t >> 6;
    const int m = l & 15, g = l >> 4;
    const int ms = m & 7;
    const int row0 = blockIdx.x * 128;
    const int col0 = blockIdx.y * 64;

    int xr[4], xsw[4];
#pragma unroll
    for (int i = 0; i < 4; ++i) {
        const int c = w * 256 + i * 64 + l;
        xr[i]  = c >> 3;
        xsw[i] = ((c & 7) ^ (xr[i] & 7)) * 8;
    }
    int wr[2], wsw[2];
#pragma unroll
    for (int i = 0; i < 2; ++i) {
        const int c = w * 128 + i * 64 + l;
        wr[i]  = c >> 3;
        wsw[i] = ((c & 7) ^ (wr[i] & 7)) * 8;
    }

#pragma unroll
    for (int i = 0; i < 4; ++i)
        async16(&Xs[0][(w * 256 + i * 64) * 8], X + (size_t)(row0 + xr[i]) * DM + xsw[i]);
#pragma unroll
    for (int i = 0; i < 2; ++i)
        async16(&Ws[0][(w * 128 + i * 64) * 8], W + (size_t)(col0 + wr[i]) * DM + wsw[i]);

    f32x4 acc[2][4] = {};

    for (int k0 = 0; k0 < DM; k0 += 64) {
        const int p = (k0 >> 6) & 1;
        __syncthreads();
        if (k0 + 64 < DM) {
            const int kn = k0 + 64;
#pragma unroll
            for (int i = 0; i < 4; ++i)
                async16(&Xs[p ^ 1][(w * 256 + i * 64) * 8],
                        X + (size_t)(row0 + xr[i]) * DM + kn + xsw[i]);
#pragma unroll
            for (int i = 0; i < 2; ++i)
                async16(&Ws[p ^ 1][(w * 128 + i * 64) * 8],
                        W + (size_t)(col0 + wr[i]) * DM + kn + wsw[i]);
        }
#pragma unroll
        for (int kk = 0; kk < 2; ++kk) {
            const int slot = ((kk * 4 + g) ^ ms) * 8;
            f16x8 a0 = *(const f16x8*)&Xs[p][(w * 32 + m) * 64 + slot];
            f16x8 a1 = *(const f16x8*)&Xs[p][(w * 32 + 16 + m) * 64 + slot];
#pragma unroll
            for (int ct = 0; ct < 4; ++ct) {
                f16x8 bf = *(const f16x8*)&Ws[p][(ct * 16 + m) * 64 + slot];
                acc[0][ct] = MFMA16(a0, bf, acc[0][ct]);
                acc[1][ct] = MFMA16(a1, bf, acc[1][ct]);
            }
        }
    }

    float bv4[4];
#pragma unroll
    for (int ct = 0; ct < 4; ++ct) bv4[ct] = bias[col0 + ct * 16 + m];

#pragma unroll
    for (int rt = 0; rt < 2; ++rt)
#pragma unroll
        for (int reg = 0; reg < 4; ++reg) {
            const int row = row0 + w * 32 + rt * 16 + g * 4 + reg;
#pragma unroll
            for (int ct = 0; ct < 4; ++ct)
                out[(size_t)row * DM + col0 + ct * 16 + m] = acc[rt][ct][reg] + bv4[ct];
        }
}

// ---------------------------------------------------------------------------
// Flash attention, KV-split x2. Q(log2e-scaled),K f16 [B*H,S,64];
// VT f16 [B*H,64,S]; mw fp32 [B][S] (pre-scaled mask, folded into the MFMA
// C-init). Each split z covers kv in [z*2048, z*2048+2048) and writes a
// per-split-NORMALIZED partial Op f16 [z][bh][q][64] plus Ml f32x2 {m,l}.
// grid (S/64, B*H, 2), block 256. Defer-max (THR=8, lane-local check).
// PV B-frag via wave-private P staging in LDS (4 ds_write_b64 + 2
// ds_read_b128 per tile) -- no ds_bpermute.
// ---------------------------------------------------------------------------
__global__ __launch_bounds__(256) void flash_mfma(
    const _Float16* __restrict__ Q, const _Float16* __restrict__ K,
    const _Float16* __restrict__ VT, const float* __restrict__ mw,
    _Float16* __restrict__ Op, float* __restrict__ Ml)
{
    __shared__ _Float16 Ks [2][64 * 64];
    __shared__ _Float16 VTs[2][64 * 64];
    __shared__ unsigned Ps[4][16 * PSTR];   // per-wave P pairs: [q-row m][pair p]

    const int t = threadIdx.x;
    const int l = t & 63, w = t >> 6;
    const int m = l & 15, g = l >> 4;
    const int bh = blockIdx.y;
    const int b  = bh >> 3;
    const int q0 = blockIdx.x * 64;
    const int z  = blockIdx.z;
    const int kb0 = z * KVS;

    const _Float16* Qh  = Q  + (size_t)bh * SEQ * DH;
    const _Float16* Kh  = K  + (size_t)bh * SEQ * DH;
    const _Float16* VTh = VT + (size_t)bh * DH * SEQ;
    const float* mwb = mw + (size_t)b * SEQ;

    const int c0 = w * 128 + l, c1 = c0 + 64;
    const int r0 = c0 >> 3,     r1 = c1 >> 3;
    const int cl0 = (c0 & 7) ^ (r0 & 7), cl1 = (c1 & 7) ^ (r1 & 7);
    const int    gK0 = r0 * DH + cl0 * 8, gK1 = r1 * DH + cl1 * 8;
    const size_t gV0 = (size_t)r0 * SEQ + cl0 * 8, gV1 = (size_t)r1 * SEQ + cl1 * 8;
    const int ldsA = w * 1024, ldsB = ldsA + 512;

    async16(&Ks[0][ldsA], Kh + (size_t)kb0 * DH + gK0);
    async16(&Ks[0][ldsB], Kh + (size_t)kb0 * DH + gK1);
    async16(&VTs[0][ldsA], VTh + kb0 + gV0);
    async16(&VTs[0][ldsB], VTh + kb0 + gV1);

    // Q fragments in registers (wave w only needs q-row w*16 + m)
    f16x8 qf[2];
#pragma unroll
    for (int kk = 0; kk < 2; ++kk)
        qf[kk] = *(const f16x8*)(Qh + (size_t)(q0 + w * 16 + m) * DH + kk * 32 + g * 8);

    float m_r = -INFINITY, l_r = 0.f;
    f32x4 oacc[4] = {};

    unsigned* Pw = &Ps[w][0];
    const int pwr = m * PSTR + g * 2;   // write base: pairs kt*8 + 2g (+1)
    const int prd = m * PSTR + g * 4;   // read base: pairs kk*16 + 4g (+0..3)
    const int ms = m & 7;

    for (int it = 0; it < KVS / 64; ++it) {
        const int t0 = kb0 + it * 64;
        const int p  = it & 1;
        __syncthreads();   // tile t0 landed

        if (it + 1 < KVS / 64) {
            const int tn = t0 + 64;
            async16(&Ks[p ^ 1][ldsA], Kh + (size_t)tn * DH + gK0);
            async16(&Ks[p ^ 1][ldsB], Kh + (size_t)tn * DH + gK1);
            async16(&VTs[p ^ 1][ldsA], VTh + tn + gV0);
            async16(&VTs[p ^ 1][ldsB], VTh + tn + gV1);
        }

        // ---- S^T = K Q^T + mask (mask pre-scaled, as MFMA C-init) ----
        f32x4 sacc[4];
#pragma unroll
        for (int kt = 0; kt < 4; ++kt)
            sacc[kt] = *(const f32x4*)&mwb[t0 + kt * 16 + g * 4];
#pragma unroll
        for (int kk = 0; kk < 2; ++kk) {
            const int slot = ((kk * 4 + g) ^ ms) * 8;
#pragma unroll
            for (int kt = 0; kt < 4; ++kt) {
                f16x8 kf = *(const f16x8*)&Ks[p][(kt * 16 + m) * 64 + slot];
                sacc[kt] = MFMA16(kf, qf[kk], sacc[kt]);
            }
        }

        // ---- online softmax, scalar state per lane (one q-row each) ----
        // lane-local max over this lane's 16 scores (v_max3 tree)
        const float x0 = m3(sacc[0][0], sacc[0][1], sacc[0][2]);
        const float x1 = m3(sacc[0][3], sacc[1][0], sacc[1][1]);
        const float x2 = m3(sacc[1][2], sacc[1][3], sacc[2][0]);
        const float x3 = m3(sacc[2][1], sacc[2][2], sacc[2][3]);
        const float x4 = m3(sacc[3][0], sacc[3][1], sacc[3][2]);
        const float lmax = fmaxf(m3(x0, x1, x2), m3(x3, x4, sacc[3][3]));

        // defer-max, lane-local check: row max = max of 4 lane maxes, so
        // all-lanes-within-bound implies all rows within bound (P <= 2^8,
        // f16-safe). Only on failure do the cross-lane reduce + rescale;
        // m_r stays row-uniform (updated only with row-reduced values).
        if (!__all(lmax <= m_r + 8.f)) {
            float r = fmaxf(lmax, __shfl_xor(lmax, 16));
            r = fmaxf(r, __shfl_xor(r, 32));
            const float mnew  = fmaxf(m_r, r);
            const float alpha = EXP2(m_r - mnew);   // first tile: exp2(-inf)=0
            m_r = mnew;
            l_r *= alpha;
#pragma unroll
            for (int dt = 0; dt < 4; ++dt)
#pragma unroll
                for (int r4 = 0; r4 < 4; ++r4) oacc[dt][r4] *= alpha;
        }

        // ---- P = exp2(S - m); pack to f16 pairs; stage to wave-private LDS.
        //      Lane (m,g) holds pairs kt*8 + 2g (+1) of row m.          ----
        float ps0 = 0.f, ps1 = 0.f;
#pragma unroll
        for (int kt = 0; kt < 4; ++kt) {
            const float p0 = EXP2(sacc[kt][0] - m_r);
            const float p1 = EXP2(sacc[kt][1] - m_r);
            const float p2 = EXP2(sacc[kt][2] - m_r);
            const float p3 = EXP2(sacc[kt][3] - m_r);
            const unsigned u0 = pk_f16(p0, p1);
            const unsigned u1 = pk_f16(p2, p3);
            *(uint2*)&Pw[pwr + kt * 8] = make_uint2(u0, u1);   // ds_write_b64
            if (kt < 2) {
                ps0 = dot2acc(u0, ps0);
                ps0 = dot2acc(u1, ps0);
            } else {
                ps1 = dot2acc(u0, ps1);
                ps1 = dot2acc(u1, ps1);
            }
        }
        l_r += ps0 + ps1;

        // ---- O^T += V^T P^T ; B-frag = pairs kk*16 + 4g + {0..3} of row m
        //      (one ds_read_b128 per kk; equals the old sel_shfl gather) ----
#pragma unroll
        for (int kk = 0; kk < 2; ++kk) {
            union { uint4 u4; f16x8 h; } pf;
            pf.u4 = *(const uint4*)&Pw[prd + kk * 16];
            const int slot = ((kk * 4 + g) ^ ms) * 8;
#pragma unroll
            for (int dt = 0; dt < 4; ++dt) {
                f16x8 vf = *(const f16x8*)&VTs[p][(dt * 16 + m) * 64 + slot];
                oacc[dt] = MFMA16(vf, pf.h, oacc[dt]);
            }
        }
    }

    // ---- final l reduction + per-split-normalized partial store ----
    l_r += __shfl_xor(l_r, 16);
    l_r += __shfl_xor(l_r, 32);
    const float inv = 1.0f / l_r;
    const int q = q0 + w * 16 + m;
    const size_t rowi = ((size_t)z * NB * NH + bh) * SEQ + q;
    _Float16* Orow = Op + rowi * DH;
#pragma unroll
    for (int dt = 0; dt < 4; ++dt) {
        _Float16 o4[4] = { (_Float16)(oacc[dt][0] * inv), (_Float16)(oacc[dt][1] * inv),
                           (_Float16)(oacc[dt][2] * inv), (_Float16)(oacc[dt][3] * inv) };
        *(uint2*)(Orow + dt * 16 + g * 4) = *(const uint2*)o4;
    }
    if (g == 0) ((float2*)Ml)[rowi] = make_float2(m_r, l_r);
}

// ---------------------------------------------------------------------------
// Combine the 2 KV-splits: O = (a0*O0n + a1*O1n) / (a0+a1),
// a_z = exp2(m_z - M) * l_z  (exact, defer-max-safe). 16 threads per q-row,
// 4 d each. grid (RH*16/256) x 256. Writes Ows f16 [B,S,512].
// ---------------------------------------------------------------------------
__global__ __launch_bounds__(256) void combine(const _Float16* __restrict__ Op,
                                               const float* __restrict__ Ml,
                                               _Float16* __restrict__ O)
{
    const int i = blockIdx.x * 256 + threadIdx.x;
    const int r = i >> 4;            // bh*SEQ + q
    const int dq = (i & 15) * 4;
    const float2 ml0 = ((const float2*)Ml)[r];
    const float2 ml1 = ((const float2*)Ml)[RH + r];
    const float M = fmaxf(ml0.x, ml1.x);
    float a0 = EXP2(ml0.x - M) * ml0.y;
    float a1 = EXP2(ml1.x - M) * ml1.y;
    const float inv = 1.f / (a0 + a1);
    a0 *= inv; a1 *= inv;
    union { uint2 u; _Float16 h[4]; } v0, v1, o;
    v0.u = *(const uint2*)(Op + (size_t)r * DH + dq);
    v1.u = *(const uint2*)(Op + ((size_t)RH + r) * DH + dq);
#pragma unroll
    for (int j = 0; j < 4; ++j)
        o.h[j] = (_Float16)(a0 * (float)v0.h[j] + a1 * (float)v1.h[j]);
    const int bh = r >> 12, q = r & (SEQ - 1);
    const int b = bh >> 3, h = bh & 7;
    *(uint2*)(O + ((size_t)b * SEQ + q) * DM + h * DH + dq) = o.u;
}

extern "C" void kernel_launch(void* const* d_in, const int* in_sizes, int n_in,
                              void* d_out, int out_size, void* d_ws, size_t ws_size,
                              hipStream_t stream) {
    const float* q    = (const float*)d_in[0];
    const float* k    = (const float*)d_in[1];
    const float* v    = (const float*)d_in[2];
    const float* mask = (const float*)d_in[3];
    const float* wq   = (const float*)d_in[4];
    const float* bq   = (const float*)d_in[5];
    const float* wk   = (const float*)d_in[6];
    const float* bk   = (const float*)d_in[7];
    const float* wv   = (const float*)d_in[8];
    const float* bv   = (const float*)d_in[9];
    const float* wo   = (const float*)d_in[10];
    const float* bo   = (const float*)d_in[11];

    // workspace (~59 MB): Wt 2MB | mw 32KB | Qin,Kin,Vin f16 | Qws,Kws,VTws,Ows f16
    // After proj3, Qin/Kin/Vin are dead: Opart (16MB) reuses Qin+Kin exactly,
    // Ml (1MB) reuses Vin.
    const size_t P8 = (size_t)MR * DM;
    _Float16* Wt  = (_Float16*)d_ws;
    float*    mw  = (float*)(Wt + (size_t)4 * DM * DM);
    _Float16* Qin = (_Float16*)(mw + NB * SEQ);
    _Float16* Kin = Qin + P8;
    _Float16* Vin = Kin + P8;
    _Float16* Qws = Vin + P8;
    _Float16* Kws = Qws + P8;
    _Float16* VTws = Kws + P8;
    _Float16* Ows  = VTws + P8;

    _Float16* Opart = Qin;          // 2*16*4096*64 f16 = 16 MB (spans Qin+Kin)
    float*    Mlb   = (float*)Vin;  // 2*65536*2 f32 = 1 MB

    cvt_w<<<dim3(8, 8, 4), 256, 0, stream>>>(wq, wk, wv, wo, Wt);
    maskprep<<<dim3(NB * SEQ / 256), 256, 0, stream>>>(mask, mw);
    cvt_qkv<<<dim3(3 * (MR * DM / 8) / 256), 256, 0, stream>>>(q, k, v, Qin, Kin, Vin);

    proj3<<<dim3(MR / 128, DM / 64, 3), 256, 0, stream>>>(
        Qin, Kin, Vin, Wt, bq, bk, bv, Qws, Kws, VTws);

    flash_mfma<<<dim3(SEQ / 64, NB * NH, NSPL), 256, 0, stream>>>(
        Qws, Kws, VTws, mw, Opart, Mlb);

    combine<<<dim3(RH * 16 / 256), 256, 0, stream>>>(Opart, Mlb, Ows);

    gemm_out<<<dim3(MR / 128, DM / 64), 256, 0, stream>>>(
        Ows, Wt + (size_t)3 * DM * DM, bo, (float*)d_out);
}

// Round 7
// 260.824 us; speedup vs baseline: 1.1315x; 1.0811x over previous
//
#include <hip/hip_runtime.h>

// MultiHeadAttention: B=2, S=4096, D=512, H=8, depth=64. fp32 in/out.
// mfma_f32_16x16x32_f16 everywhere, fp32 accum. S^T = K Q^T flash (one q-row
// per lane), async double-buffered global_load_lds staging in ALL matmul
// kernels. Round 18: flash is still LDS-READ-bound (83% LDS-busy; K/V
// ds_read_b128 = 54% of wall). QBLK=32 per wave (two q-halves) amortizes
// every K/V fragment read over two MFMAs -- viable now because R6's P-LDS
// round-trip killed the pkw/sel_shfl register pressure that sank the R4
// QBLK=32 attempt (250 regs -> ~150). __launch_bounds__(256,3) pins 3
// waves/SIMD; LDS 51.2KB = 3 blocks/CU (LDS-capped). Per-half softmax is
// processed sequentially to keep sacc peak at one half. Defer-max (THR=8,
// lane-local), v_max3 tree, dot2 psum, mask-as-C-init retained. NSPL=2.
#define NH   8
#define DH   64
#define NB   2
#define SEQ  4096
#define DM   512
#define MR   (NB * SEQ)
#define LSTR 72
#define LOG2E 1.44269504089f
#define NSPL 2
#define KVS  (SEQ / NSPL)
#define RH   (NB * NH * SEQ)   // 65536 q-rows across heads/splits
#define PSTR 36                // P_lds row stride in u32 (even, mult of 4)

using f16x8 = __attribute__((ext_vector_type(8))) _Float16;
using f32x4 = __attribute__((ext_vector_type(4))) float;
using h2    = __attribute__((ext_vector_type(2))) _Float16;
#define MFMA16(a, b, c) __builtin_amdgcn_mfma_f32_16x16x32_f16(a, b, c, 0, 0, 0)

#if defined(__has_builtin) && __has_builtin(__builtin_amdgcn_exp2f)
#define EXP2(x) __builtin_amdgcn_exp2f(x)
#else
extern "C" __device__ float __ocml_native_exp2_f32(float);
#define EXP2(x) __ocml_native_exp2_f32(x)
#endif

__device__ __forceinline__ unsigned pk_f16(float a, float b) {
    typedef __fp16 fp16v2 __attribute__((ext_vector_type(2)));
    union { fp16v2 h; unsigned u; } c;
    c.h = __builtin_amdgcn_cvt_pkrtz(a, b);
    return c.u;
}
__device__ __forceinline__ float m3(float a, float b, float c) {
    return fmaxf(fmaxf(a, b), c);   // fuses to v_max3_f32
}
// l-sum accumulate from a packed f16 pair: c += p.lo + p.hi
__device__ __forceinline__ float dot2acc(unsigned u, float c) {
#if defined(__has_builtin) && __has_builtin(__builtin_amdgcn_fdot2)
    h2 a = __builtin_bit_cast(h2, u);
    h2 one = {(_Float16)1.f, (_Float16)1.f};
    return __builtin_amdgcn_fdot2(a, one, c, false);
#else
    h2 a = __builtin_bit_cast(h2, u);
    return c + (float)a[0] + (float)a[1];
#endif
}
// async 16B/lane global -> LDS (lds dest = wave-uniform base + lane*16)
__device__ __forceinline__ void async16(void* lds, const void* g) {
    __builtin_amdgcn_global_load_lds(
        (__attribute__((address_space(1))) void*)g,
        (__attribute__((address_space(3))) void*)lds, 16, 0, 0);
}

// ---------------------------------------------------------------------------
// W fp32 [k][n] -> Wt f16 [n][k], 4 weights. grid (8,8,4) x 256.
// ---------------------------------------------------------------------------
__global__ __launch_bounds__(256) void cvt_w(
    const float* __restrict__ w0, const float* __restrict__ w1,
    const float* __restrict__ w2, const float* __restrict__ w3,
    _Float16* __restrict__ Wt)
{
    __shared__ _Float16 T[64 * LSTR];
    const int z = blockIdx.z;
    const float* W = (z == 0) ? w0 : (z == 1 ? w1 : (z == 2 ? w2 : w3));
    _Float16* out = Wt + (size_t)z * DM * DM;
    const int t = threadIdx.x;
    const int k0 = blockIdx.x * 64, n0 = blockIdx.y * 64;
#pragma unroll
    for (int i = 0; i < 4; ++i) {
        const int kl  = i * 16 + (t >> 4);
        const int nl4 = (t & 15) * 4;
        float4 u = *(const float4*)(W + (size_t)(k0 + kl) * DM + n0 + nl4);
        T[(nl4 + 0) * LSTR + kl] = (_Float16)u.x;
        T[(nl4 + 1) * LSTR + kl] = (_Float16)u.y;
        T[(nl4 + 2) * LSTR + kl] = (_Float16)u.z;
        T[(nl4 + 3) * LSTR + kl] = (_Float16)u.w;
    }
    __syncthreads();
#pragma unroll
    for (int i = 0; i < 2; ++i) {
        const int nl = i * 32 + (t >> 3);
        const int kc = (t & 7) * 8;
        *(uint4*)(out + (size_t)(n0 + nl) * DM + k0 + kc) = *(const uint4*)&T[nl * LSTR + kc];
    }
}

// mask [B,1,1,S] fp32 -> mw = mask * (-1e9*log2e). grid 32 x 256.
__global__ __launch_bounds__(256) void maskprep(const float* __restrict__ mask,
                                                float* __restrict__ mw)
{
    const int i = blockIdx.x * 256 + threadIdx.x;
    mw[i] = mask[i] * (-1e9f * LOG2E);
}

// q,k,v fp32 -> f16 flat [MR][DM]. grid 6144 x 256, 8 elems/thread.
__global__ __launch_bounds__(256) void cvt_qkv(
    const float* __restrict__ q, const float* __restrict__ k,
    const float* __restrict__ v,
    _Float16* __restrict__ Qo, _Float16* __restrict__ Ko, _Float16* __restrict__ Vo)
{
    const size_t PER = (size_t)MR * DM;
    size_t base = ((size_t)blockIdx.x * 256 + threadIdx.x) * 8;
    const int tz = (int)(base / PER);
    const size_t off = base % PER;
    const float* s = (tz == 0) ? q : (tz == 1 ? k : v);
    _Float16* d    = (tz == 0) ? Qo : (tz == 1 ? Ko : Vo);
    float4 a = *(const float4*)(s + off);
    float4 b = *(const float4*)(s + off + 4);
    uint4 p = make_uint4(pk_f16(a.x, a.y), pk_f16(a.z, a.w),
                         pk_f16(b.x, b.y), pk_f16(b.z, b.w));
    *(uint4*)(d + off) = p;
}

// ---------------------------------------------------------------------------
// Fused QKV projection, async double-buffered. X f16 [M][512] by z;
// Wt f16 [3][n][k]. z<2: head-split f16 [B,H,S,64] (Q scaled by log2e);
// z==2: transposed [B,H,64,S]. grid (MR/128, 8, 3), block 256.
// LDS swizzle: chunk c -> row c>>3, slot c&7; data for column-chunk
// ((c&7)^(row&7)) stored there (swizzle applied on the global address side).
// ---------------------------------------------------------------------------
__global__ __launch_bounds__(256) void proj3(
    const _Float16* __restrict__ Qin, const _Float16* __restrict__ Kin,
    const _Float16* __restrict__ Vin, const _Float16* __restrict__ Wt,
    const float* __restrict__ bq, const float* __restrict__ bk,
    const float* __restrict__ bv,
    _Float16* __restrict__ Qo, _Float16* __restrict__ Ko,
    _Float16* __restrict__ VTo)
{
    __shared__ _Float16 Xs[2][128 * 64];
    __shared__ _Float16 Ws[2][64 * 64];

    const int z = blockIdx.z;
    const _Float16* X = (z == 0) ? Qin : (z == 1 ? Kin : Vin);
    const _Float16* W = Wt + (size_t)z * DM * DM;
    const float* bias = (z == 0) ? bq : (z == 1 ? bk : bv);
    const float scale = (z == 0) ? LOG2E : 1.0f;

    const int t = threadIdx.x;
    const int l = t & 63, w = t >> 6;
    const int m = l & 15, g = l >> 4;
    const int ms = m & 7;
    const int row0 = blockIdx.x * 128;
    const int col0 = blockIdx.y * 64;

    int xr[4], xsw[4];
#pragma unroll
    for (int i = 0; i < 4; ++i) {
        const int c = w * 256 + i * 64 + l;
        xr[i]  = c >> 3;
        xsw[i] = ((c & 7) ^ (xr[i] & 7)) * 8;
    }
    int wr[2], wsw[2];
#pragma unroll
    for (int i = 0; i < 2; ++i) {
        const int c = w * 128 + i * 64 + l;
        wr[i]  = c >> 3;
        wsw[i] = ((c & 7) ^ (wr[i] & 7)) * 8;
    }

    // prologue: k0 = 0 into buffer 0
#pragma unroll
    for (int i = 0; i < 4; ++i)
        async16(&Xs[0][(w * 256 + i * 64) * 8], X + (size_t)(row0 + xr[i]) * DM + xsw[i]);
#pragma unroll
    for (int i = 0; i < 2; ++i)
        async16(&Ws[0][(w * 128 + i * 64) * 8], W + (size_t)(col0 + wr[i]) * DM + wsw[i]);

    f32x4 acc[2][4] = {};

    for (int k0 = 0; k0 < DM; k0 += 64) {
        const int p = (k0 >> 6) & 1;
        __syncthreads();   // drains tile k0 (issued a full compute-phase ago)
        if (k0 + 64 < DM) {
            const int kn = k0 + 64;
#pragma unroll
            for (int i = 0; i < 4; ++i)
                async16(&Xs[p ^ 1][(w * 256 + i * 64) * 8],
                        X + (size_t)(row0 + xr[i]) * DM + kn + xsw[i]);
#pragma unroll
            for (int i = 0; i < 2; ++i)
                async16(&Ws[p ^ 1][(w * 128 + i * 64) * 8],
                        W + (size_t)(col0 + wr[i]) * DM + kn + wsw[i]);
        }
#pragma unroll
        for (int kk = 0; kk < 2; ++kk) {
            const int slot = ((kk * 4 + g) ^ ms) * 8;
            f16x8 a0 = *(const f16x8*)&Xs[p][(w * 32 + m) * 64 + slot];
            f16x8 a1 = *(const f16x8*)&Xs[p][(w * 32 + 16 + m) * 64 + slot];
#pragma unroll
            for (int ct = 0; ct < 4; ++ct) {
                f16x8 bf = *(const f16x8*)&Ws[p][(ct * 16 + m) * 64 + slot];
                acc[0][ct] = MFMA16(a0, bf, acc[0][ct]);
                acc[1][ct] = MFMA16(a1, bf, acc[1][ct]);
            }
        }
    }

    float bv4[4];
#pragma unroll
    for (int ct = 0; ct < 4; ++ct) bv4[ct] = bias[col0 + ct * 16 + m];

    if (z == 2) {
        __syncthreads();   // all waves done reading Xs
        _Float16* T = &Xs[0][0];   // reuse as T[64][136]
#pragma unroll
        for (int rt = 0; rt < 2; ++rt)
#pragma unroll
            for (int reg = 0; reg < 4; ++reg) {
                const int s_l = w * 32 + rt * 16 + g * 4 + reg;
#pragma unroll
                for (int ct = 0; ct < 4; ++ct) {
                    const int d = ct * 16 + m;
                    T[d * 136 + s_l] = (_Float16)(acc[rt][ct][reg] + bv4[ct]);
                }
            }
        __syncthreads();
        const int bb = row0 >> 12;
        const int s0 = row0 & (SEQ - 1);
#pragma unroll
        for (int j = 0; j < 4; ++j) {
            const int c = j * 256 + t;
            const int d = c >> 4;
            const int sc = (c & 15) * 8;
            *(uint4*)(VTo + (((size_t)bb * NH + blockIdx.y) * DH + d) * SEQ + s0 + sc) =
                *(const uint4*)&T[d * 136 + sc];
        }
    } else {
        _Float16* out = (z == 0) ? Qo : Ko;
#pragma unroll
        for (int rt = 0; rt < 2; ++rt)
#pragma unroll
            for (int reg = 0; reg < 4; ++reg) {
                const int row = row0 + w * 32 + rt * 16 + g * 4 + reg;
                const int bb = row >> 12;
                const int s  = row & (SEQ - 1);
#pragma unroll
                for (int ct = 0; ct < 4; ++ct)
                    out[(((size_t)bb * NH + blockIdx.y) * SEQ + s) * DH + ct * 16 + m] =
                        (_Float16)(scale * (acc[rt][ct][reg] + bv4[ct]));
            }
    }
}

// ---------------------------------------------------------------------------
// Output GEMM: d_out[M,512] fp32 = Ows[M,512](f16) @ Wo + bo. Async dbuf.
// grid (MR/128, 8), block 256.
// ---------------------------------------------------------------------------
__global__ __launch_bounds__(256) void gemm_out(const _Float16* __restrict__ X,
                                                const _Float16* __restrict__ W,
                                                const float* __restrict__ bias,
                                                float* __restrict__ out)
{
    __shared__ _Float16 Xs[2][128 * 64];
    __shared__ _Float16 Ws[2][64 * 64];

    const int t = threadIdx.x;
    const int l = t & 63, w = t >> 6;
    const int m = l & 15, g = l >> 4;
    const int ms = m & 7;
    const int row0 = blockIdx.x * 128;
    const int col0 = blockIdx.y * 64;

    int xr[4], xsw[4];
#pragma unroll
    for (int i = 0; i < 4; ++i) {
        const int c = w * 256 + i * 64 + l;
        xr[i]  = c >> 3;
        xsw[i] = ((c & 7) ^ (xr[i] & 7)) * 8;
    }
    int wr[2], wsw[2];
#pragma unroll
    for (int i = 0; i < 2; ++i) {
        const int c = w * 128 + i * 64 + l;
        wr[i]  = c >> 3;
        wsw[i] = ((c & 7) ^ (wr[i] & 7)) * 8;
    }

#pragma unroll
    for (int i = 0; i < 4; ++i)
        async16(&Xs[0][(w * 256 + i * 64) * 8], X + (size_t)(row0 + xr[i]) * DM + xsw[i]);
#pragma unroll
    for (int i = 0; i < 2; ++i)
        async16(&Ws[0][(w * 128 + i * 64) * 8], W + (size_t)(col0 + wr[i]) * DM + wsw[i]);

    f32x4 acc[2][4] = {};

    for (int k0 = 0; k0 < DM; k0 += 64) {
        const int p = (k0 >> 6) & 1;
        __syncthreads();
        if (k0 + 64 < DM) {
            const int kn = k0 + 64;
#pragma unroll
            for (int i = 0; i < 4; ++i)
                async16(&Xs[p ^ 1][(w * 256 + i * 64) * 8],
                        X + (size_t)(row0 + xr[i]) * DM + kn + xsw[i]);
#pragma unroll
            for (int i = 0; i < 2; ++i)
                async16(&Ws[p ^ 1][(w * 128 + i * 64) * 8],
                        W + (size_t)(col0 + wr[i]) * DM + kn + wsw[i]);
        }
#pragma unroll
        for (int kk = 0; kk < 2; ++kk) {
            const int slot = ((kk * 4 + g) ^ ms) * 8;
            f16x8 a0 = *(const f16x8*)&Xs[p][(w * 32 + m) * 64 + slot];
            f16x8 a1 = *(const f16x8*)&Xs[p][(w * 32 + 16 + m) * 64 + slot];
#pragma unroll
            for (int ct = 0; ct < 4; ++ct) {
                f16x8 bf = *(const f16x8*)&Ws[p][(ct * 16 + m) * 64 + slot];
                acc[0][ct] = MFMA16(a0, bf, acc[0][ct]);
                acc[1][ct] = MFMA16(a1, bf, acc[1][ct]);
            }
        }
    }

    float bv4[4];
#pragma unroll
    for (int ct = 0; ct < 4; ++ct) bv4[ct] = bias[col0 + ct * 16 + m];

#pragma unroll
    for (int rt = 0; rt < 2; ++rt)
#pragma unroll
        for (int reg = 0; reg < 4; ++reg) {
            const int row = row0 + w * 32 + rt * 16 + g * 4 + reg;
#pragma unroll
            for (int ct = 0; ct < 4; ++ct)
                out[(size_t)row * DM + col0 + ct * 16 + m] = acc[rt][ct][reg] + bv4[ct];
        }
}

// ---------------------------------------------------------------------------
// Flash attention, KV-split x2, 32 q-rows per wave (two 16-row halves).
// Q(log2e-scaled),K f16 [B*H,S,64]; VT f16 [B*H,64,S]; mw fp32 [B][S]
// (pre-scaled mask, folded into the MFMA C-init). Split z covers kv in
// [z*2048, z*2048+2048); writes per-split-NORMALIZED partial Op f16
// [z][bh][q][64] plus Ml f32x2 {m,l}. grid (S/128, B*H, 2), block 256.
// Every K/V LDS fragment read feeds TWO MFMAs (one per q-half); PV B-frags
// via wave-private P staging in LDS (no ds_bpermute, no pkw registers).
// __launch_bounds__(256,3): 3 waves/SIMD target; LDS 51.2KB = 3 blocks/CU.
// ---------------------------------------------------------------------------
__global__ __launch_bounds__(256, 3) void flash_mfma(
    const _Float16* __restrict__ Q, const _Float16* __restrict__ K,
    const _Float16* __restrict__ VT, const float* __restrict__ mw,
    _Float16* __restrict__ Op, float* __restrict__ Ml)
{
    __shared__ _Float16 Ks [2][64 * 64];
    __shared__ _Float16 VTs[2][64 * 64];
    __shared__ unsigned Ps[4][32 * PSTR];   // per-wave P pairs: [q-row][pair]

    const int t = threadIdx.x;
    const int l = t & 63, w = t >> 6;
    const int m = l & 15, g = l >> 4;
    const int bh = blockIdx.y;
    const int b  = bh >> 3;
    const int q0 = blockIdx.x * 128;
    const int z  = blockIdx.z;
    const int kb0 = z * KVS;

    const _Float16* Qh  = Q  + (size_t)bh * SEQ * DH;
    const _Float16* Kh  = K  + (size_t)bh * SEQ * DH;
    const _Float16* VTh = VT + (size_t)bh * DH * SEQ;
    const float* mwb = mw + (size_t)b * SEQ;

    const int c0 = w * 128 + l, c1 = c0 + 64;
    const int r0 = c0 >> 3,     r1 = c1 >> 3;
    const int cl0 = (c0 & 7) ^ (r0 & 7), cl1 = (c1 & 7) ^ (r1 & 7);
    const int    gK0 = r0 * DH + cl0 * 8, gK1 = r1 * DH + cl1 * 8;
    const size_t gV0 = (size_t)r0 * SEQ + cl0 * 8, gV1 = (size_t)r1 * SEQ + cl1 * 8;
    const int ldsA = w * 1024, ldsB = ldsA + 512;

    async16(&Ks[0][ldsA], Kh + (size_t)kb0 * DH + gK0);
    async16(&Ks[0][ldsB], Kh + (size_t)kb0 * DH + gK1);
    async16(&VTs[0][ldsA], VTh + kb0 + gV0);
    async16(&VTs[0][ldsB], VTh + kb0 + gV1);

    // Q fragments in registers: wave w covers q-rows q0 + w*32 + {0..15,16..31}
    f16x8 qf[2][2];
#pragma unroll
    for (int h = 0; h < 2; ++h)
#pragma unroll
        for (int kk = 0; kk < 2; ++kk)
            qf[h][kk] = *(const f16x8*)(Qh + (size_t)(q0 + w * 32 + h * 16 + m) * DH +
                                        kk * 32 + g * 8);

    float m_r[2] = {-INFINITY, -INFINITY}, l_r[2] = {0.f, 0.f};
    f32x4 oacc[2][4] = {};

    unsigned* Pw = &Ps[w][0];
    const int ms = m & 7;

    for (int it = 0; it < KVS / 64; ++it) {
        const int t0 = kb0 + it * 64;
        const int p  = it & 1;
        __syncthreads();   // tile t0 landed

        if (it + 1 < KVS / 64) {
            const int tn = t0 + 64;
            async16(&Ks[p ^ 1][ldsA], Kh + (size_t)tn * DH + gK0);
            async16(&Ks[p ^ 1][ldsB], Kh + (size_t)tn * DH + gK1);
            async16(&VTs[p ^ 1][ldsA], VTh + tn + gV0);
            async16(&VTs[p ^ 1][ldsB], VTh + tn + gV1);
        }

        // ---- S^T = K Q^T + mask; each kf read feeds both q-halves ----
        f32x4 sacc[2][4];
#pragma unroll
        for (int kt = 0; kt < 4; ++kt) {
            const f32x4 mv = *(const f32x4*)&mwb[t0 + kt * 16 + g * 4];
            sacc[0][kt] = mv;
            sacc[1][kt] = mv;
        }
#pragma unroll
        for (int kk = 0; kk < 2; ++kk) {
            const int slot = ((kk * 4 + g) ^ ms) * 8;
#pragma unroll
            for (int kt = 0; kt < 4; ++kt) {
                f16x8 kf = *(const f16x8*)&Ks[p][(kt * 16 + m) * 64 + slot];
                sacc[0][kt] = MFMA16(kf, qf[0][kk], sacc[0][kt]);
                sacc[1][kt] = MFMA16(kf, qf[1][kk], sacc[1][kt]);
            }
        }

        // ---- online softmax per half (sequential: sacc[h] dies as used) ----
        float lmax[2];
#pragma unroll
        for (int h = 0; h < 2; ++h) {
            const float x0 = m3(sacc[h][0][0], sacc[h][0][1], sacc[h][0][2]);
            const float x1 = m3(sacc[h][0][3], sacc[h][1][0], sacc[h][1][1]);
            const float x2 = m3(sacc[h][1][2], sacc[h][1][3], sacc[h][2][0]);
            const float x3 = m3(sacc[h][2][1], sacc[h][2][2], sacc[h][2][3]);
            const float x4 = m3(sacc[h][3][0], sacc[h][3][1], sacc[h][3][2]);
            lmax[h] = fmaxf(m3(x0, x1, x2), m3(x3, x4, sacc[h][3][3]));
        }

        // defer-max, lane-local check (row max = max of 4 lane maxes ->
        // all-lanes-in-bound implies all rows in bound; P <= 2^8, f16-safe)
        if (!__all(lmax[0] <= m_r[0] + 8.f && lmax[1] <= m_r[1] + 8.f)) {
#pragma unroll
            for (int h = 0; h < 2; ++h) {
                float r = fmaxf(lmax[h], __shfl_xor(lmax[h], 16));
                r = fmaxf(r, __shfl_xor(r, 32));
                const float mnew  = fmaxf(m_r[h], r);
                const float alpha = EXP2(m_r[h] - mnew);   // first tile: 0
                m_r[h] = mnew;
                l_r[h] *= alpha;
#pragma unroll
                for (int dt = 0; dt < 4; ++dt)
#pragma unroll
                    for (int r4 = 0; r4 < 4; ++r4) oacc[h][dt][r4] *= alpha;
            }
        }

        // ---- P = exp2(S - m); pack; stage to wave-private LDS rows h*16+m ----
#pragma unroll
        for (int h = 0; h < 2; ++h) {
            const int pwr = (h * 16 + m) * PSTR + g * 2;
            float ps0 = 0.f, ps1 = 0.f;
#pragma unroll
            for (int kt = 0; kt < 4; ++kt) {
                const float p0 = EXP2(sacc[h][kt][0] - m_r[h]);
                const float p1 = EXP2(sacc[h][kt][1] - m_r[h]);
                const float p2 = EXP2(sacc[h][kt][2] - m_r[h]);
                const float p3 = EXP2(sacc[h][kt][3] - m_r[h]);
                const unsigned u0 = pk_f16(p0, p1);
                const unsigned u1 = pk_f16(p2, p3);
                *(uint2*)&Pw[pwr + kt * 8] = make_uint2(u0, u1);   // ds_write_b64
                if (kt < 2) {
                    ps0 = dot2acc(u0, ps0);
                    ps0 = dot2acc(u1, ps0);
                } else {
                    ps1 = dot2acc(u0, ps1);
                    ps1 = dot2acc(u1, ps1);
                }
            }
            l_r[h] += ps0 + ps1;
        }

        // ---- O^T += V^T P^T ; each vf read feeds both q-halves ----
#pragma unroll
        for (int kk = 0; kk < 2; ++kk) {
            union { uint4 u4; f16x8 h; } pf[2];
#pragma unroll
            for (int h = 0; h < 2; ++h)
                pf[h].u4 = *(const uint4*)&Pw[(h * 16 + m) * PSTR + kk * 16 + g * 4];
            const int slot = ((kk * 4 + g) ^ ms) * 8;
#pragma unroll
            for (int dt = 0; dt < 4; ++dt) {
                f16x8 vf = *(const f16x8*)&VTs[p][(dt * 16 + m) * 64 + slot];
                oacc[0][dt] = MFMA16(vf, pf[0].h, oacc[0][dt]);
                oacc[1][dt] = MFMA16(vf, pf[1].h, oacc[1][dt]);
            }
        }
    }

    // ---- final l reduction + per-split-normalized partial store ----
#pragma unroll
    for (int h = 0; h < 2; ++h) {
        float lv = l_r[h];
        lv += __shfl_xor(lv, 16);
        lv += __shfl_xor(lv, 32);
        const float inv = 1.0f / lv;
        const int q = q0 + w * 32 + h * 16 + m;
        const size_t rowi = ((size_t)z * NB * NH + bh) * SEQ + q;
        _Float16* Orow = Op + rowi * DH;
#pragma unroll
        for (int dt = 0; dt < 4; ++dt) {
            _Float16 o4[4] = { (_Float16)(oacc[h][dt][0] * inv),
                               (_Float16)(oacc[h][dt][1] * inv),
                               (_Float16)(oacc[h][dt][2] * inv),
                               (_Float16)(oacc[h][dt][3] * inv) };
            *(uint2*)(Orow + dt * 16 + g * 4) = *(const uint2*)o4;
        }
        if (g == 0) ((float2*)Ml)[rowi] = make_float2(m_r[h], lv);
    }
}

// ---------------------------------------------------------------------------
// Combine the 2 KV-splits: O = (a0*O0n + a1*O1n) / (a0+a1),
// a_z = exp2(m_z - M) * l_z  (exact, defer-max-safe). 16 threads per q-row,
// 4 d each. grid (RH*16/256) x 256. Writes Ows f16 [B,S,512].
// ---------------------------------------------------------------------------
__global__ __launch_bounds__(256) void combine(const _Float16* __restrict__ Op,
                                               const float* __restrict__ Ml,
                                               _Float16* __restrict__ O)
{
    const int i = blockIdx.x * 256 + threadIdx.x;
    const int r = i >> 4;            // bh*SEQ + q
    const int dq = (i & 15) * 4;
    const float2 ml0 = ((const float2*)Ml)[r];
    const float2 ml1 = ((const float2*)Ml)[RH + r];
    const float M = fmaxf(ml0.x, ml1.x);
    float a0 = EXP2(ml0.x - M) * ml0.y;
    float a1 = EXP2(ml1.x - M) * ml1.y;
    const float inv = 1.f / (a0 + a1);
    a0 *= inv; a1 *= inv;
    union { uint2 u; _Float16 h[4]; } v0, v1, o;
    v0.u = *(const uint2*)(Op + (size_t)r * DH + dq);
    v1.u = *(const uint2*)(Op + ((size_t)RH + r) * DH + dq);
#pragma unroll
    for (int j = 0; j < 4; ++j)
        o.h[j] = (_Float16)(a0 * (float)v0.h[j] + a1 * (float)v1.h[j]);
    const int bh = r >> 12, q = r & (SEQ - 1);
    const int b = bh >> 3, h = bh & 7;
    *(uint2*)(O + ((size_t)b * SEQ + q) * DM + h * DH + dq) = o.u;
}

extern "C" void kernel_launch(void* const* d_in, const int* in_sizes, int n_in,
                              void* d_out, int out_size, void* d_ws, size_t ws_size,
                              hipStream_t stream) {
    const float* q    = (const float*)d_in[0];
    const float* k    = (const float*)d_in[1];
    const float* v    = (const float*)d_in[2];
    const float* mask = (const float*)d_in[3];
    const float* wq   = (const float*)d_in[4];
    const float* bq   = (const float*)d_in[5];
    const float* wk   = (const float*)d_in[6];
    const float* bk   = (const float*)d_in[7];
    const float* wv   = (const float*)d_in[8];
    const float* bv   = (const float*)d_in[9];
    const float* wo   = (const float*)d_in[10];
    const float* bo   = (const float*)d_in[11];

    // workspace (~59 MB): Wt 2MB | mw 32KB | Qin,Kin,Vin f16 | Qws,Kws,VTws,Ows f16
    // After proj3, Qin/Kin/Vin are dead: Opart (16MB) reuses Qin+Kin exactly,
    // Ml (1MB) reuses Vin.
    const size_t P8 = (size_t)MR * DM;
    _Float16* Wt  = (_Float16*)d_ws;
    float*    mw  = (float*)(Wt + (size_t)4 * DM * DM);
    _Float16* Qin = (_Float16*)(mw + NB * SEQ);
    _Float16* Kin = Qin + P8;
    _Float16* Vin = Kin + P8;
    _Float16* Qws = Vin + P8;
    _Float16* Kws = Qws + P8;
    _Float16* VTws = Kws + P8;
    _Float16* Ows  = VTws + P8;

    _Float16* Opart = Qin;          // 2*16*4096*64 f16 = 16 MB (spans Qin+Kin)
    float*    Mlb   = (float*)Vin;  // 2*65536*2 f32 = 1 MB

    cvt_w<<<dim3(8, 8, 4), 256, 0, stream>>>(wq, wk, wv, wo, Wt);
    maskprep<<<dim3(NB * SEQ / 256), 256, 0, stream>>>(mask, mw);
    cvt_qkv<<<dim3(3 * (MR * DM / 8) / 256), 256, 0, stream>>>(q, k, v, Qin, Kin, Vin);

    proj3<<<dim3(MR / 128, DM / 64, 3), 256, 0, stream>>>(
        Qin, Kin, Vin, Wt, bq, bk, bv, Qws, Kws, VTws);

    flash_mfma<<<dim3(SEQ / 128, NB * NH, NSPL), 256, 0, stream>>>(
        Qws, Kws, VTws, mw, Opart, Mlb);

    combine<<<dim3(RH * 16 / 256), 256, 0, stream>>>(Opart, Mlb, Ows);

    gemm_out<<<dim3(MR / 128, DM / 64), 256, 0, stream>>>(
        Ows, Wt + (size_t)3 * DM * DM, bo, (float*)d_out);
}

// Round 8
// 250.323 us; speedup vs baseline: 1.1790x; 1.0419x over previous
//
#include <hip/hip_runtime.h>

// MultiHeadAttention: B=2, S=4096, D=512, H=8, depth=64. fp32 in/out.
// mfma_f32_16x16x32_f16 everywhere, fp32 accum. S^T = K Q^T flash (one q-row
// per lane), async double-buffered global_load_lds staging in ALL matmul
// kernels. Round 19: R7 (QBLK=32 + wave-private P-LDS, 3 blocks/CU) is
// latency-bound, not pipe-bound. Three latency cuts in flash: (1) XCD-
// bijective block swizzle (w -> (w&7)*128 + w>>3) so the 32 q-blocks
// sharing one (bh,z) K/V panel land on ONE XCD's L2 (512KB panel, L2-hit
// instead of HBM re-fetch per XCD); (2) next-tile mask prefetched into
// registers (C-init no longer gates the first MFMA on a global round-trip);
// (3) f32x4 vector sub for S-m (packed v_pk_add_f32). Defer-max (THR=8,
// lane-local), v_max3 tree, dot2 psum retained. NSPL=2.
#define NH   8
#define DH   64
#define NB   2
#define SEQ  4096
#define DM   512
#define MR   (NB * SEQ)
#define LSTR 72
#define LOG2E 1.44269504089f
#define NSPL 2
#define KVS  (SEQ / NSPL)
#define RH   (NB * NH * SEQ)   // 65536 q-rows across heads/splits
#define PSTR 36                // P_lds row stride in u32 (even, mult of 4)

using f16x8 = __attribute__((ext_vector_type(8))) _Float16;
using f32x4 = __attribute__((ext_vector_type(4))) float;
using h2    = __attribute__((ext_vector_type(2))) _Float16;
#define MFMA16(a, b, c) __builtin_amdgcn_mfma_f32_16x16x32_f16(a, b, c, 0, 0, 0)

#if defined(__has_builtin) && __has_builtin(__builtin_amdgcn_exp2f)
#define EXP2(x) __builtin_amdgcn_exp2f(x)
#else
extern "C" __device__ float __ocml_native_exp2_f32(float);
#define EXP2(x) __ocml_native_exp2_f32(x)
#endif

__device__ __forceinline__ unsigned pk_f16(float a, float b) {
    typedef __fp16 fp16v2 __attribute__((ext_vector_type(2)));
    union { fp16v2 h; unsigned u; } c;
    c.h = __builtin_amdgcn_cvt_pkrtz(a, b);
    return c.u;
}
__device__ __forceinline__ float m3(float a, float b, float c) {
    return fmaxf(fmaxf(a, b), c);   // fuses to v_max3_f32
}
// l-sum accumulate from a packed f16 pair: c += p.lo + p.hi
__device__ __forceinline__ float dot2acc(unsigned u, float c) {
#if defined(__has_builtin) && __has_builtin(__builtin_amdgcn_fdot2)
    h2 a = __builtin_bit_cast(h2, u);
    h2 one = {(_Float16)1.f, (_Float16)1.f};
    return __builtin_amdgcn_fdot2(a, one, c, false);
#else
    h2 a = __builtin_bit_cast(h2, u);
    return c + (float)a[0] + (float)a[1];
#endif
}
// async 16B/lane global -> LDS (lds dest = wave-uniform base + lane*16)
__device__ __forceinline__ void async16(void* lds, const void* g) {
    __builtin_amdgcn_global_load_lds(
        (__attribute__((address_space(1))) void*)g,
        (__attribute__((address_space(3))) void*)lds, 16, 0, 0);
}

// ---------------------------------------------------------------------------
// W fp32 [k][n] -> Wt f16 [n][k], 4 weights. grid (8,8,4) x 256.
// ---------------------------------------------------------------------------
__global__ __launch_bounds__(256) void cvt_w(
    const float* __restrict__ w0, const float* __restrict__ w1,
    const float* __restrict__ w2, const float* __restrict__ w3,
    _Float16* __restrict__ Wt)
{
    __shared__ _Float16 T[64 * LSTR];
    const int z = blockIdx.z;
    const float* W = (z == 0) ? w0 : (z == 1 ? w1 : (z == 2 ? w2 : w3));
    _Float16* out = Wt + (size_t)z * DM * DM;
    const int t = threadIdx.x;
    const int k0 = blockIdx.x * 64, n0 = blockIdx.y * 64;
#pragma unroll
    for (int i = 0; i < 4; ++i) {
        const int kl  = i * 16 + (t >> 4);
        const int nl4 = (t & 15) * 4;
        float4 u = *(const float4*)(W + (size_t)(k0 + kl) * DM + n0 + nl4);
        T[(nl4 + 0) * LSTR + kl] = (_Float16)u.x;
        T[(nl4 + 1) * LSTR + kl] = (_Float16)u.y;
        T[(nl4 + 2) * LSTR + kl] = (_Float16)u.z;
        T[(nl4 + 3) * LSTR + kl] = (_Float16)u.w;
    }
    __syncthreads();
#pragma unroll
    for (int i = 0; i < 2; ++i) {
        const int nl = i * 32 + (t >> 3);
        const int kc = (t & 7) * 8;
        *(uint4*)(out + (size_t)(n0 + nl) * DM + k0 + kc) = *(const uint4*)&T[nl * LSTR + kc];
    }
}

// mask [B,1,1,S] fp32 -> mw = mask * (-1e9*log2e). grid 32 x 256.
__global__ __launch_bounds__(256) void maskprep(const float* __restrict__ mask,
                                                float* __restrict__ mw)
{
    const int i = blockIdx.x * 256 + threadIdx.x;
    mw[i] = mask[i] * (-1e9f * LOG2E);
}

// q,k,v fp32 -> f16 flat [MR][DM]. grid 6144 x 256, 8 elems/thread.
__global__ __launch_bounds__(256) void cvt_qkv(
    const float* __restrict__ q, const float* __restrict__ k,
    const float* __restrict__ v,
    _Float16* __restrict__ Qo, _Float16* __restrict__ Ko, _Float16* __restrict__ Vo)
{
    const size_t PER = (size_t)MR * DM;
    size_t base = ((size_t)blockIdx.x * 256 + threadIdx.x) * 8;
    const int tz = (int)(base / PER);
    const size_t off = base % PER;
    const float* s = (tz == 0) ? q : (tz == 1 ? k : v);
    _Float16* d    = (tz == 0) ? Qo : (tz == 1 ? Ko : Vo);
    float4 a = *(const float4*)(s + off);
    float4 b = *(const float4*)(s + off + 4);
    uint4 p = make_uint4(pk_f16(a.x, a.y), pk_f16(a.z, a.w),
                         pk_f16(b.x, b.y), pk_f16(b.z, b.w));
    *(uint4*)(d + off) = p;
}

// ---------------------------------------------------------------------------
// Fused QKV projection, async double-buffered. X f16 [M][512] by z;
// Wt f16 [3][n][k]. z<2: head-split f16 [B,H,S,64] (Q scaled by log2e);
// z==2: transposed [B,H,64,S]. grid (MR/128, 8, 3), block 256.
// LDS swizzle: chunk c -> row c>>3, slot c&7; data for column-chunk
// ((c&7)^(row&7)) stored there (swizzle applied on the global address side).
// ---------------------------------------------------------------------------
__global__ __launch_bounds__(256) void proj3(
    const _Float16* __restrict__ Qin, const _Float16* __restrict__ Kin,
    const _Float16* __restrict__ Vin, const _Float16* __restrict__ Wt,
    const float* __restrict__ bq, const float* __restrict__ bk,
    const float* __restrict__ bv,
    _Float16* __restrict__ Qo, _Float16* __restrict__ Ko,
    _Float16* __restrict__ VTo)
{
    __shared__ _Float16 Xs[2][128 * 64];
    __shared__ _Float16 Ws[2][64 * 64];

    const int z = blockIdx.z;
    const _Float16* X = (z == 0) ? Qin : (z == 1 ? Kin : Vin);
    const _Float16* W = Wt + (size_t)z * DM * DM;
    const float* bias = (z == 0) ? bq : (z == 1 ? bk : bv);
    const float scale = (z == 0) ? LOG2E : 1.0f;

    const int t = threadIdx.x;
    const int l = t & 63, w = t >> 6;
    const int m = l & 15, g = l >> 4;
    const int ms = m & 7;
    const int row0 = blockIdx.x * 128;
    const int col0 = blockIdx.y * 64;

    int xr[4], xsw[4];
#pragma unroll
    for (int i = 0; i < 4; ++i) {
        const int c = w * 256 + i * 64 + l;
        xr[i]  = c >> 3;
        xsw[i] = ((c & 7) ^ (xr[i] & 7)) * 8;
    }
    int wr[2], wsw[2];
#pragma unroll
    for (int i = 0; i < 2; ++i) {
        const int c = w * 128 + i * 64 + l;
        wr[i]  = c >> 3;
        wsw[i] = ((c & 7) ^ (wr[i] & 7)) * 8;
    }

    // prologue: k0 = 0 into buffer 0
#pragma unroll
    for (int i = 0; i < 4; ++i)
        async16(&Xs[0][(w * 256 + i * 64) * 8], X + (size_t)(row0 + xr[i]) * DM + xsw[i]);
#pragma unroll
    for (int i = 0; i < 2; ++i)
        async16(&Ws[0][(w * 128 + i * 64) * 8], W + (size_t)(col0 + wr[i]) * DM + wsw[i]);

    f32x4 acc[2][4] = {};

    for (int k0 = 0; k0 < DM; k0 += 64) {
        const int p = (k0 >> 6) & 1;
        __syncthreads();   // drains tile k0 (issued a full compute-phase ago)
        if (k0 + 64 < DM) {
            const int kn = k0 + 64;
#pragma unroll
            for (int i = 0; i < 4; ++i)
                async16(&Xs[p ^ 1][(w * 256 + i * 64) * 8],
                        X + (size_t)(row0 + xr[i]) * DM + kn + xsw[i]);
#pragma unroll
            for (int i = 0; i < 2; ++i)
                async16(&Ws[p ^ 1][(w * 128 + i * 64) * 8],
                        W + (size_t)(col0 + wr[i]) * DM + kn + wsw[i]);
        }
#pragma unroll
        for (int kk = 0; kk < 2; ++kk) {
            const int slot = ((kk * 4 + g) ^ ms) * 8;
            f16x8 a0 = *(const f16x8*)&Xs[p][(w * 32 + m) * 64 + slot];
            f16x8 a1 = *(const f16x8*)&Xs[p][(w * 32 + 16 + m) * 64 + slot];
#pragma unroll
            for (int ct = 0; ct < 4; ++ct) {
                f16x8 bf = *(const f16x8*)&Ws[p][(ct * 16 + m) * 64 + slot];
                acc[0][ct] = MFMA16(a0, bf, acc[0][ct]);
                acc[1][ct] = MFMA16(a1, bf, acc[1][ct]);
            }
        }
    }

    float bv4[4];
#pragma unroll
    for (int ct = 0; ct < 4; ++ct) bv4[ct] = bias[col0 + ct * 16 + m];

    if (z == 2) {
        __syncthreads();   // all waves done reading Xs
        _Float16* T = &Xs[0][0];   // reuse as T[64][136]
#pragma unroll
        for (int rt = 0; rt < 2; ++rt)
#pragma unroll
            for (int reg = 0; reg < 4; ++reg) {
                const int s_l = w * 32 + rt * 16 + g * 4 + reg;
#pragma unroll
                for (int ct = 0; ct < 4; ++ct) {
                    const int d = ct * 16 + m;
                    T[d * 136 + s_l] = (_Float16)(acc[rt][ct][reg] + bv4[ct]);
                }
            }
        __syncthreads();
        const int bb = row0 >> 12;
        const int s0 = row0 & (SEQ - 1);
#pragma unroll
        for (int j = 0; j < 4; ++j) {
            const int c = j * 256 + t;
            const int d = c >> 4;
            const int sc = (c & 15) * 8;
            *(uint4*)(VTo + (((size_t)bb * NH + blockIdx.y) * DH + d) * SEQ + s0 + sc) =
                *(const uint4*)&T[d * 136 + sc];
        }
    } else {
        _Float16* out = (z == 0) ? Qo : Ko;
#pragma unroll
        for (int rt = 0; rt < 2; ++rt)
#pragma unroll
            for (int reg = 0; reg < 4; ++reg) {
                const int row = row0 + w * 32 + rt * 16 + g * 4 + reg;
                const int bb = row >> 12;
                const int s  = row & (SEQ - 1);
#pragma unroll
                for (int ct = 0; ct < 4; ++ct)
                    out[(((size_t)bb * NH + blockIdx.y) * SEQ + s) * DH + ct * 16 + m] =
                        (_Float16)(scale * (acc[rt][ct][reg] + bv4[ct]));
            }
    }
}

// ---------------------------------------------------------------------------
// Output GEMM: d_out[M,512] fp32 = Ows[M,512](f16) @ Wo + bo. Async dbuf.
// grid (MR/128, 8), block 256.
// ---------------------------------------------------------------------------
__global__ __launch_bounds__(256) void gemm_out(const _Float16* __restrict__ X,
                                                const _Float16* __restrict__ W,
                                                const float* __restrict__ bias,
                                                float* __restrict__ out)
{
    __shared__ _Float16 Xs[2][128 * 64];
    __shared__ _Float16 Ws[2][64 * 64];

    const int t = threadIdx.x;
    const int l = t & 63, w = t >> 6;
    const int m = l & 15, g = l >> 4;
    const int ms = m & 7;
    const int row0 = blockIdx.x * 128;
    const int col0 = blockIdx.y * 64;

    int xr[4], xsw[4];
#pragma unroll
    for (int i = 0; i < 4; ++i) {
        const int c = w * 256 + i * 64 + l;
        xr[i]  = c >> 3;
        xsw[i] = ((c & 7) ^ (xr[i] & 7)) * 8;
    }
    int wr[2], wsw[2];
#pragma unroll
    for (int i = 0; i < 2; ++i) {
        const int c = w * 128 + i * 64 + l;
        wr[i]  = c >> 3;
        wsw[i] = ((c & 7) ^ (wr[i] & 7)) * 8;
    }

#pragma unroll
    for (int i = 0; i < 4; ++i)
        async16(&Xs[0][(w * 256 + i * 64) * 8], X + (size_t)(row0 + xr[i]) * DM + xsw[i]);
#pragma unroll
    for (int i = 0; i < 2; ++i)
        async16(&Ws[0][(w * 128 + i * 64) * 8], W + (size_t)(col0 + wr[i]) * DM + wsw[i]);

    f32x4 acc[2][4] = {};

    for (int k0 = 0; k0 < DM; k0 += 64) {
        const int p = (k0 >> 6) & 1;
        __syncthreads();
        if (k0 + 64 < DM) {
            const int kn = k0 + 64;
#pragma unroll
            for (int i = 0; i < 4; ++i)
                async16(&Xs[p ^ 1][(w * 256 + i * 64) * 8],
                        X + (size_t)(row0 + xr[i]) * DM + kn + xsw[i]);
#pragma unroll
            for (int i = 0; i < 2; ++i)
                async16(&Ws[p ^ 1][(w * 128 + i * 64) * 8],
                        W + (size_t)(col0 + wr[i]) * DM + kn + wsw[i]);
        }
#pragma unroll
        for (int kk = 0; kk < 2; ++kk) {
            const int slot = ((kk * 4 + g) ^ ms) * 8;
            f16x8 a0 = *(const f16x8*)&Xs[p][(w * 32 + m) * 64 + slot];
            f16x8 a1 = *(const f16x8*)&Xs[p][(w * 32 + 16 + m) * 64 + slot];
#pragma unroll
            for (int ct = 0; ct < 4; ++ct) {
                f16x8 bf = *(const f16x8*)&Ws[p][(ct * 16 + m) * 64 + slot];
                acc[0][ct] = MFMA16(a0, bf, acc[0][ct]);
                acc[1][ct] = MFMA16(a1, bf, acc[1][ct]);
            }
        }
    }

    float bv4[4];
#pragma unroll
    for (int ct = 0; ct < 4; ++ct) bv4[ct] = bias[col0 + ct * 16 + m];

#pragma unroll
    for (int rt = 0; rt < 2; ++rt)
#pragma unroll
        for (int reg = 0; reg < 4; ++reg) {
            const int row = row0 + w * 32 + rt * 16 + g * 4 + reg;
#pragma unroll
            for (int ct = 0; ct < 4; ++ct)
                out[(size_t)row * DM + col0 + ct * 16 + m] = acc[rt][ct][reg] + bv4[ct];
        }
}

// ---------------------------------------------------------------------------
// Flash attention, KV-split x2, 32 q-rows per wave (two 16-row halves).
// Q(log2e-scaled),K f16 [B*H,S,64]; VT f16 [B*H,64,S]; mw fp32 [B][S]
// (pre-scaled mask, MFMA C-init, register-prefetched one tile ahead).
// Split z covers kv in [z*2048, z*2048+2048); writes per-split-NORMALIZED
// partial Op f16 [z][bh][q][64] plus Ml f32x2 {m,l}. grid (S/128, B*H, 2)
// with XCD-bijective swizzle: flat w -> o=(w&7)*128 + w>>3, so the 32
// q-blocks sharing one (bh,z) K/V panel (512KB, L2-resident) run on ONE
// XCD. Every K/V LDS fragment read feeds TWO MFMAs (one per q-half); PV
// B-frags via wave-private P staging in LDS. __launch_bounds__(256,3).
// ---------------------------------------------------------------------------
__global__ __launch_bounds__(256, 3) void flash_mfma(
    const _Float16* __restrict__ Q, const _Float16* __restrict__ K,
    const _Float16* __restrict__ VT, const float* __restrict__ mw,
    _Float16* __restrict__ Op, float* __restrict__ Ml)
{
    __shared__ _Float16 Ks [2][64 * 64];
    __shared__ _Float16 VTs[2][64 * 64];
    __shared__ unsigned Ps[4][32 * PSTR];   // per-wave P pairs: [q-row][pair]

    const int t = threadIdx.x;
    const int l = t & 63, w = t >> 6;
    const int m = l & 15, g = l >> 4;

    // XCD-bijective swizzle (1024 blocks, 1024 % 8 == 0)
    const unsigned wfl = blockIdx.x + 32u * blockIdx.y + 512u * blockIdx.z;
    const unsigned o   = (wfl & 7u) * 128u + (wfl >> 3);
    const int q0 = (int)(o & 31u) * 128;
    const int bh = (int)(o >> 5) & 15;
    const int z  = (int)(o >> 9);
    const int b  = bh >> 3;
    const int kb0 = z * KVS;

    const _Float16* Qh  = Q  + (size_t)bh * SEQ * DH;
    const _Float16* Kh  = K  + (size_t)bh * SEQ * DH;
    const _Float16* VTh = VT + (size_t)bh * DH * SEQ;
    const float* mwb = mw + (size_t)b * SEQ;

    const int c0 = w * 128 + l, c1 = c0 + 64;
    const int r0 = c0 >> 3,     r1 = c1 >> 3;
    const int cl0 = (c0 & 7) ^ (r0 & 7), cl1 = (c1 & 7) ^ (r1 & 7);
    const int    gK0 = r0 * DH + cl0 * 8, gK1 = r1 * DH + cl1 * 8;
    const size_t gV0 = (size_t)r0 * SEQ + cl0 * 8, gV1 = (size_t)r1 * SEQ + cl1 * 8;
    const int ldsA = w * 1024, ldsB = ldsA + 512;

    async16(&Ks[0][ldsA], Kh + (size_t)kb0 * DH + gK0);
    async16(&Ks[0][ldsB], Kh + (size_t)kb0 * DH + gK1);
    async16(&VTs[0][ldsA], VTh + kb0 + gV0);
    async16(&VTs[0][ldsB], VTh + kb0 + gV1);

    // Q fragments in registers: wave w covers q-rows q0 + w*32 + {0..15,16..31}
    f16x8 qf[2][2];
#pragma unroll
    for (int h = 0; h < 2; ++h)
#pragma unroll
        for (int kk = 0; kk < 2; ++kk)
            qf[h][kk] = *(const f16x8*)(Qh + (size_t)(q0 + w * 32 + h * 16 + m) * DH +
                                        kk * 32 + g * 8);

    // mask C-init for tile 0, register-prefetched
    f32x4 mv[4];
#pragma unroll
    for (int kt = 0; kt < 4; ++kt)
        mv[kt] = *(const f32x4*)&mwb[kb0 + kt * 16 + g * 4];

    float m_r[2] = {-INFINITY, -INFINITY}, l_r[2] = {0.f, 0.f};
    f32x4 oacc[2][4] = {};

    unsigned* Pw = &Ps[w][0];
    const int ms = m & 7;

    for (int it = 0; it < KVS / 64; ++it) {
        const int t0 = kb0 + it * 64;
        const int p  = it & 1;
        const bool more = (it + 1 < KVS / 64);
        __syncthreads();   // tile t0 landed

        f32x4 mvn[4];
        if (more) {
            const int tn = t0 + 64;
            async16(&Ks[p ^ 1][ldsA], Kh + (size_t)tn * DH + gK0);
            async16(&Ks[p ^ 1][ldsB], Kh + (size_t)tn * DH + gK1);
            async16(&VTs[p ^ 1][ldsA], VTh + tn + gV0);
            async16(&VTs[p ^ 1][ldsB], VTh + tn + gV1);
            // prefetch next tile's mask into registers (off critical path)
#pragma unroll
            for (int kt = 0; kt < 4; ++kt)
                mvn[kt] = *(const f32x4*)&mwb[tn + kt * 16 + g * 4];
        }

        // ---- S^T = K Q^T + mask; each kf read feeds both q-halves ----
        f32x4 sacc[2][4];
#pragma unroll
        for (int kt = 0; kt < 4; ++kt) {
            sacc[0][kt] = mv[kt];
            sacc[1][kt] = mv[kt];
        }
#pragma unroll
        for (int kk = 0; kk < 2; ++kk) {
            const int slot = ((kk * 4 + g) ^ ms) * 8;
#pragma unroll
            for (int kt = 0; kt < 4; ++kt) {
                f16x8 kf = *(const f16x8*)&Ks[p][(kt * 16 + m) * 64 + slot];
                sacc[0][kt] = MFMA16(kf, qf[0][kk], sacc[0][kt]);
                sacc[1][kt] = MFMA16(kf, qf[1][kk], sacc[1][kt]);
            }
        }

        // ---- online softmax per half (sequential: sacc[h] dies as used) ----
        float lmax[2];
#pragma unroll
        for (int h = 0; h < 2; ++h) {
            const float x0 = m3(sacc[h][0][0], sacc[h][0][1], sacc[h][0][2]);
            const float x1 = m3(sacc[h][0][3], sacc[h][1][0], sacc[h][1][1]);
            const float x2 = m3(sacc[h][1][2], sacc[h][1][3], sacc[h][2][0]);
            const float x3 = m3(sacc[h][2][1], sacc[h][2][2], sacc[h][2][3]);
            const float x4 = m3(sacc[h][3][0], sacc[h][3][1], sacc[h][3][2]);
            lmax[h] = fmaxf(m3(x0, x1, x2), m3(x3, x4, sacc[h][3][3]));
        }

        // defer-max, lane-local check (row max = max of 4 lane maxes ->
        // all-lanes-in-bound implies all rows in bound; P <= 2^8, f16-safe)
        if (!__all(lmax[0] <= m_r[0] + 8.f && lmax[1] <= m_r[1] + 8.f)) {
#pragma unroll
            for (int h = 0; h < 2; ++h) {
                float r = fmaxf(lmax[h], __shfl_xor(lmax[h], 16));
                r = fmaxf(r, __shfl_xor(r, 32));
                const float mnew  = fmaxf(m_r[h], r);
                const float alpha = EXP2(m_r[h] - mnew);   // first tile: 0
                m_r[h] = mnew;
                l_r[h] *= alpha;
#pragma unroll
                for (int dt = 0; dt < 4; ++dt)
#pragma unroll
                    for (int r4 = 0; r4 < 4; ++r4) oacc[h][dt][r4] *= alpha;
            }
        }

        // ---- P = exp2(S - m); pack; stage to wave-private LDS rows h*16+m ----
#pragma unroll
        for (int h = 0; h < 2; ++h) {
            const int pwr = (h * 16 + m) * PSTR + g * 2;
            const f32x4 mh = {m_r[h], m_r[h], m_r[h], m_r[h]};
            float ps0 = 0.f, ps1 = 0.f;
#pragma unroll
            for (int kt = 0; kt < 4; ++kt) {
                const f32x4 d = sacc[h][kt] - mh;   // packed v_pk_add_f32
                const float p0 = EXP2(d[0]);
                const float p1 = EXP2(d[1]);
                const float p2 = EXP2(d[2]);
                const float p3 = EXP2(d[3]);
                const unsigned u0 = pk_f16(p0, p1);
                const unsigned u1 = pk_f16(p2, p3);
                *(uint2*)&Pw[pwr + kt * 8] = make_uint2(u0, u1);   // ds_write_b64
                if (kt < 2) {
                    ps0 = dot2acc(u0, ps0);
                    ps0 = dot2acc(u1, ps0);
                } else {
                    ps1 = dot2acc(u0, ps1);
                    ps1 = dot2acc(u1, ps1);
                }
            }
            l_r[h] += ps0 + ps1;
        }

        // ---- O^T += V^T P^T ; each vf read feeds both q-halves ----
#pragma unroll
        for (int kk = 0; kk < 2; ++kk) {
            union { uint4 u4; f16x8 h; } pf[2];
#pragma unroll
            for (int h = 0; h < 2; ++h)
                pf[h].u4 = *(const uint4*)&Pw[(h * 16 + m) * PSTR + kk * 16 + g * 4];
            const int slot = ((kk * 4 + g) ^ ms) * 8;
#pragma unroll
            for (int dt = 0; dt < 4; ++dt) {
                f16x8 vf = *(const f16x8*)&VTs[p][(dt * 16 + m) * 64 + slot];
                oacc[0][dt] = MFMA16(vf, pf[0].h, oacc[0][dt]);
                oacc[1][dt] = MFMA16(vf, pf[1].h, oacc[1][dt]);
            }
        }

        if (more) {
#pragma unroll
            for (int kt = 0; kt < 4; ++kt) mv[kt] = mvn[kt];
        }
    }

    // ---- final l reduction + per-split-normalized partial store ----
#pragma unroll
    for (int h = 0; h < 2; ++h) {
        float lv = l_r[h];
        lv += __shfl_xor(lv, 16);
        lv += __shfl_xor(lv, 32);
        const float inv = 1.0f / lv;
        const int q = q0 + w * 32 + h * 16 + m;
        const size_t rowi = ((size_t)z * NB * NH + bh) * SEQ + q;
        _Float16* Orow = Op + rowi * DH;
#pragma unroll
        for (int dt = 0; dt < 4; ++dt) {
            _Float16 o4[4] = { (_Float16)(oacc[h][dt][0] * inv),
                               (_Float16)(oacc[h][dt][1] * inv),
                               (_Float16)(oacc[h][dt][2] * inv),
                               (_Float16)(oacc[h][dt][3] * inv) };
            *(uint2*)(Orow + dt * 16 + g * 4) = *(const uint2*)o4;
        }
        if (g == 0) ((float2*)Ml)[rowi] = make_float2(m_r[h], lv);
    }
}

// ---------------------------------------------------------------------------
// Combine the 2 KV-splits: O = (a0*O0n + a1*O1n) / (a0+a1),
// a_z = exp2(m_z - M) * l_z  (exact, defer-max-safe). 16 threads per q-row,
// 4 d each. grid (RH*16/256) x 256. Writes Ows f16 [B,S,512].
// ---------------------------------------------------------------------------
__global__ __launch_bounds__(256) void combine(const _Float16* __restrict__ Op,
                                               const float* __restrict__ Ml,
                                               _Float16* __restrict__ O)
{
    const int i = blockIdx.x * 256 + threadIdx.x;
    const int r = i >> 4;            // bh*SEQ + q
    const int dq = (i & 15) * 4;
    const float2 ml0 = ((const float2*)Ml)[r];
    const float2 ml1 = ((const float2*)Ml)[RH + r];
    const float M = fmaxf(ml0.x, ml1.x);
    float a0 = EXP2(ml0.x - M) * ml0.y;
    float a1 = EXP2(ml1.x - M) * ml1.y;
    const float inv = 1.f / (a0 + a1);
    a0 *= inv; a1 *= inv;
    union { uint2 u; _Float16 h[4]; } v0, v1, o;
    v0.u = *(const uint2*)(Op + (size_t)r * DH + dq);
    v1.u = *(const uint2*)(Op + ((size_t)RH + r) * DH + dq);
#pragma unroll
    for (int j = 0; j < 4; ++j)
        o.h[j] = (_Float16)(a0 * (float)v0.h[j] + a1 * (float)v1.h[j]);
    const int bh = r >> 12, q = r & (SEQ - 1);
    const int b = bh >> 3, h = bh & 7;
    *(uint2*)(O + ((size_t)b * SEQ + q) * DM + h * DH + dq) = o.u;
}

extern "C" void kernel_launch(void* const* d_in, const int* in_sizes, int n_in,
                              void* d_out, int out_size, void* d_ws, size_t ws_size,
                              hipStream_t stream) {
    const float* q    = (const float*)d_in[0];
    const float* k    = (const float*)d_in[1];
    const float* v    = (const float*)d_in[2];
    const float* mask = (const float*)d_in[3];
    const float* wq   = (const float*)d_in[4];
    const float* bq   = (const float*)d_in[5];
    const float* wk   = (const float*)d_in[6];
    const float* bk   = (const float*)d_in[7];
    const float* wv   = (const float*)d_in[8];
    const float* bv   = (const float*)d_in[9];
    const float* wo   = (const float*)d_in[10];
    const float* bo   = (const float*)d_in[11];

    // workspace (~59 MB): Wt 2MB | mw 32KB | Qin,Kin,Vin f16 | Qws,Kws,VTws,Ows f16
    // After proj3, Qin/Kin/Vin are dead: Opart (16MB) reuses Qin+Kin exactly,
    // Ml (1MB) reuses Vin.
    const size_t P8 = (size_t)MR * DM;
    _Float16* Wt  = (_Float16*)d_ws;
    float*    mw  = (float*)(Wt + (size_t)4 * DM * DM);
    _Float16* Qin = (_Float16*)(mw + NB * SEQ);
    _Float16* Kin = Qin + P8;
    _Float16* Vin = Kin + P8;
    _Float16* Qws = Vin + P8;
    _Float16* Kws = Qws + P8;
    _Float16* VTws = Kws + P8;
    _Float16* Ows  = VTws + P8;

    _Float16* Opart = Qin;          // 2*16*4096*64 f16 = 16 MB (spans Qin+Kin)
    float*    Mlb   = (float*)Vin;  // 2*65536*2 f32 = 1 MB

    cvt_w<<<dim3(8, 8, 4), 256, 0, stream>>>(wq, wk, wv, wo, Wt);
    maskprep<<<dim3(NB * SEQ / 256), 256, 0, stream>>>(mask, mw);
    cvt_qkv<<<dim3(3 * (MR * DM / 8) / 256), 256, 0, stream>>>(q, k, v, Qin, Kin, Vin);

    proj3<<<dim3(MR / 128, DM / 64, 3), 256, 0, stream>>>(
        Qin, Kin, Vin, Wt, bq, bk, bv, Qws, Kws, VTws);

    flash_mfma<<<dim3(SEQ / 128, NB * NH, NSPL), 256, 0, stream>>>(
        Qws, Kws, VTws, mw, Opart, Mlb);

    combine<<<dim3(RH * 16 / 256), 256, 0, stream>>>(Opart, Mlb, Ows);

    gemm_out<<<dim3(MR / 128, DM / 64), 256, 0, stream>>>(
        Ows, Wt + (size_t)3 * DM * DM, bo, (float*)d_out);
}